// Round 6
// baseline (375.738 us; speedup 1.0000x reference)
//
#include <hip/hip_runtime.h>
#include <cstdio>
#include <math.h>

// ---------------------------------------------------------------------------
// MeshEncoderDecoder — round 6: interleaved x1 [b][E][2][128] (one gather
// serves both branches), register-prefetch pipelined mesh2, merged decoder
// heads (shared xall gather).
// ---------------------------------------------------------------------------

#define E_TOT 50000
#define B_TOT 2
#define TILE_E 64
#define NBLK ((E_TOT + TILE_E - 1) / TILE_E)   // 782

typedef _Float16 half_t;
typedef __attribute__((ext_vector_type(4))) _Float16 h4;
typedef __attribute__((ext_vector_type(8))) _Float16 h8;
typedef __attribute__((ext_vector_type(4))) float f32x4;

__device__ __forceinline__ float sigmoidf_(float x) {
    return 1.0f / (1.0f + __expf(-x));
}
__device__ __forceinline__ h8 habs8(h8 x) {
    union { h8 h; unsigned int u[4]; } v;
    v.h = x;
#pragma unroll
    for (int i = 0; i < 4; ++i) v.u[i] &= 0x7FFF7FFFu;
    return v.h;
}

// ---------------------------------------------------------------------------
// weight arena offsets (halves)
// ---------------------------------------------------------------------------
#define OFF_W1E   0          // 128*64 (k = s*8+cc, zero-padded)
#define OFF_W1P   8192       // 128*64
#define OFF_WTE2  16384      // 128*5*128
#define OFF_WTP2  98304      // 128*5*128
#define OFF_WHA   180224     // 128*5*64 (o<64: wal in s0; o>=64: wat)
#define OFF_WHB   221184     // 128*5*64
#define OFF_WTA   262144     // 32*128
#define OFF_WTB   266240     // 32*128
#define OFF_WTAF  270336     // 128*128
#define OFF_WTBF  286720     // 128*128
#define WARENA_N  303104

__global__ __launch_bounds__(256)
void wprep_k(half_t* __restrict__ wa_,
             const float* __restrict__ w_e1, const float* __restrict__ w_p1,
             const float* __restrict__ w_e2, const float* __restrict__ w_p2,
             const float* __restrict__ wat,  const float* __restrict__ wbt,
             const float* __restrict__ wa,   const float* __restrict__ wb,
             const float* __restrict__ wal,  const float* __restrict__ wbl,
             const float* __restrict__ waf,  const float* __restrict__ wbf)
{
    int idx = blockIdx.x * 256 + threadIdx.x;
    switch (blockIdx.y) {
    case 0: if (idx < 8192) { int o = idx >> 6, k = idx & 63, s = k >> 3, cc = k & 7;
            float v = (s < 5 && cc < 5) ? w_e1[o * 25 + cc * 5 + s] : 0.f;
            wa_[OFF_W1E + idx] = (half_t)v; } break;
    case 1: if (idx < 8192) { int o = idx >> 6, k = idx & 63, s = k >> 3, cc = k & 7;
            float v = (s < 5 && cc >= 5) ? w_p1[o * 15 + (cc - 5) * 5 + s] : 0.f;
            wa_[OFF_W1P + idx] = (half_t)v; } break;
    case 2: if (idx < 81920) { int o = idx / 640, r = idx % 640, s = r >> 7, c = r & 127;
            wa_[OFF_WTE2 + idx] = (half_t)w_e2[(o * 128 + c) * 5 + s]; } break;
    case 3: if (idx < 81920) { int o = idx / 640, r = idx % 640, s = r >> 7, c = r & 127;
            wa_[OFF_WTP2 + idx] = (half_t)w_p2[(o * 128 + c) * 5 + s]; } break;
    case 4: if (idx < 40960) { int o = idx / 320, r = idx % 320, s = r >> 6, c = r & 63;
            float v = (o < 64) ? (s == 0 ? wal[o * 64 + c] : 0.f)
                               : wat[((o - 64) * 64 + c) * 5 + s];
            wa_[OFF_WHA + idx] = (half_t)v; } break;
    case 5: if (idx < 40960) { int o = idx / 320, r = idx % 320, s = r >> 6, c = r & 63;
            float v = (o < 64) ? (s == 0 ? wbl[o * 64 + c] : 0.f)
                               : wbt[((o - 64) * 64 + c) * 5 + s];
            wa_[OFF_WHB + idx] = (half_t)v; } break;
    case 6: if (idx < 4096)  wa_[OFF_WTA  + idx] = (half_t)wa[idx];  break;
    case 7: if (idx < 4096)  wa_[OFF_WTB  + idx] = (half_t)wb[idx];  break;
    case 8: if (idx < 16384) wa_[OFF_WTAF + idx] = (half_t)waf[idx]; break;
    case 9: if (idx < 16384) wa_[OFF_WTBF + idx] = (half_t)wbf[idx]; break;
    }
}

// ---------------------------------------------------------------------------
// transpose fe (b, 8, E) -> fe_t (b, E, 8) f32
// ---------------------------------------------------------------------------
__global__ __launch_bounds__(256)
void transpose_in_k(const float* __restrict__ fe, float* __restrict__ fet)
{
    int b = blockIdx.z;
    int e = blockIdx.x * 256 + threadIdx.x;
    if (e >= E_TOT) return;
    float v[8];
#pragma unroll
    for (int c = 0; c < 8; ++c)
        v[c] = fe[((long)b * 8 + c) * E_TOT + e];
    float4* dst = (float4*)&fet[((long)b * E_TOT + e) * 8];
    dst[0] = make_float4(v[0], v[1], v[2], v[3]);
    dst[1] = make_float4(v[4], v[5], v[6], v[7]);
}

// ---------------------------------------------------------------------------
// layer-1 both branches (as R5): shared G, K=64, 8 waves (0-3 edge, 4-7 point)
// ---------------------------------------------------------------------------
__global__ __launch_bounds__(512)
void mesh1_both_k(const float* __restrict__ fet, const int* __restrict__ gemm,
                  const half_t* __restrict__ war,
                  const float* __restrict__ be1, const float* __restrict__ bp1,
                  half_t* __restrict__ tmpe, half_t* __restrict__ tmpp,
                  float* __restrict__ parte, float* __restrict__ partp)
{
    __shared__ h8 Gl[64 * 8];
    __shared__ int nidx[64][4];

    const int tid  = threadIdx.x;
    const int b    = blockIdx.y;
    const int e0   = blockIdx.x * TILE_E;
    const int lane = tid & 63;
    const int wv   = tid >> 6;
    const int l15  = lane & 15;
    const int kg   = lane >> 4;
    const int br   = wv >> 2;
    const int o0   = (wv & 3) * 32;

    const float* xb = fet + (long)b * E_TOT * 8;

    if (tid < 256) {
        int e = tid >> 2, s = tid & 3;
        int eg = e0 + e;
        nidx[e][s] = (eg < E_TOT) ? gemm[((long)b * E_TOT + eg) * 4 + s] : 0;
    }
    __syncthreads();

    {
        int e = tid >> 3, g = tid & 7;
        int eg = e0 + e;
        int se = (eg < E_TOT) ? eg : 0;
        h8 r;
        if (g == 0) {
            const float* p = xb + (long)se * 8;
            float4 v0 = *(const float4*)p, v1 = *(const float4*)(p + 4);
            r[0] = (half_t)v0.x; r[1] = (half_t)v0.y; r[2] = (half_t)v0.z; r[3] = (half_t)v0.w;
            r[4] = (half_t)v1.x; r[5] = (half_t)v1.y; r[6] = (half_t)v1.z; r[7] = (half_t)v1.w;
        } else if (g <= 4) {
            int ia = (g == 1 || g == 3) ? 0 : 1;
            const float* pa = xb + (long)nidx[e][ia] * 8;
            const float* pb = xb + (long)nidx[e][ia + 2] * 8;
            float4 a0 = *(const float4*)pa, a1 = *(const float4*)(pa + 4);
            float4 b0 = *(const float4*)pb, b1 = *(const float4*)(pb + 4);
            float aa[8] = {a0.x, a0.y, a0.z, a0.w, a1.x, a1.y, a1.z, a1.w};
            float bb[8] = {b0.x, b0.y, b0.z, b0.w, b1.x, b1.y, b1.z, b1.w};
            if (g <= 2) {
#pragma unroll
                for (int j = 0; j < 8; ++j) r[j] = (half_t)(aa[j] + bb[j]);
            } else {
#pragma unroll
                for (int j = 0; j < 8; ++j) r[j] = (half_t)fabsf(aa[j] - bb[j]);
            }
        } else {
#pragma unroll
            for (int j = 0; j < 8; ++j) r[j] = (half_t)0.f;
        }
        Gl[(e * 8 + g) ^ (e & 7)] = r;
    }
    __syncthreads();

    f32x4 acc[4][2];
#pragma unroll
    for (int mt = 0; mt < 4; ++mt)
#pragma unroll
        for (int nt = 0; nt < 2; ++nt)
#pragma unroll
            for (int j = 0; j < 4; ++j) acc[mt][nt][j] = 0.f;

    const half_t* wt = war + (br ? OFF_W1P : OFF_W1E);
#pragma unroll
    for (int ks = 0; ks < 2; ++ks) {
        h8 bw[2];
#pragma unroll
        for (int nt = 0; nt < 2; ++nt)
            bw[nt] = *(const h8*)(wt + (long)(o0 + nt * 16 + l15) * 64 + ks * 32 + kg * 8);
#pragma unroll
        for (int mt = 0; mt < 4; ++mt) {
            int row = mt * 16 + l15;
            h8 a = Gl[row * 8 + ((ks * 4 + kg) ^ (row & 7))];
#pragma unroll
            for (int nt = 0; nt < 2; ++nt)
                acc[mt][nt] = __builtin_amdgcn_mfma_f32_16x16x32_f16(a, bw[nt], acc[mt][nt], 0, 0, 0);
        }
    }

    const float* bias = br ? bp1 : be1;
    half_t* yb = (br ? tmpp : tmpe) + (long)b * E_TOT * 128;
    float* part = br ? partp : parte;
    float bv[2], s1[2], s2[2];
#pragma unroll
    for (int nt = 0; nt < 2; ++nt) {
        bv[nt] = bias[o0 + nt * 16 + l15];
        s1[nt] = 0.f; s2[nt] = 0.f;
    }
#pragma unroll
    for (int mt = 0; mt < 4; ++mt) {
        int ebase = e0 + mt * 16 + (kg << 2);
#pragma unroll
        for (int j = 0; j < 4; ++j) {
            if (ebase + j < E_TOT) {
#pragma unroll
                for (int nt = 0; nt < 2; ++nt) {
                    float v = acc[mt][nt][j] + bv[nt];
                    yb[(long)(ebase + j) * 128 + o0 + nt * 16 + l15] = (half_t)v;
                    s1[nt] += v; s2[nt] += v * v;
                }
            }
        }
    }
#pragma unroll
    for (int nt = 0; nt < 2; ++nt) {
        s1[nt] += __shfl_xor(s1[nt], 16); s1[nt] += __shfl_xor(s1[nt], 32);
        s2[nt] += __shfl_xor(s2[nt], 16); s2[nt] += __shfl_xor(s2[nt], 32);
    }
    if (lane < 16) {
        long pb = ((long)b * NBLK + blockIdx.x) * 128;
#pragma unroll
        for (int nt = 0; nt < 2; ++nt) {
            part[(pb + o0 + nt * 16 + lane) * 2 + 0] = s1[nt];
            part[(pb + o0 + nt * 16 + lane) * 2 + 1] = s2[nt];
        }
    }
}

// ---------------------------------------------------------------------------
// layer-2 mesh conv, INTERLEAVED input x1i [b][E][2][128]: one block does both
// branches for a 64-edge tile. 6-phase pipeline with register prefetch.
// waves 0-3: edge branch (o-slices of 32); waves 4-7: point branch.
// ---------------------------------------------------------------------------
__global__ __launch_bounds__(512, 4)
void mesh2i_k(const half_t* __restrict__ x1i, const int* __restrict__ gemm,
              const half_t* __restrict__ war,
              const float* __restrict__ be, const float* __restrict__ bp,
              half_t* __restrict__ tmpe, half_t* __restrict__ tmpp,
              float* __restrict__ parte, float* __restrict__ partp)
{
    __shared__ h8 B0[1024], B1[1024], B2[1024], B3[1024];
    __shared__ int nidx[64][4];

    const int tid  = threadIdx.x;
    const int b    = blockIdx.y;
    const int e0   = blockIdx.x * TILE_E;
    const int lane = tid & 63;
    const int wv   = tid >> 6;
    const int br   = wv >> 2;
    const int o0   = (wv & 3) * 32;
    const int l15  = lane & 15;
    const int kg   = lane >> 4;

    const half_t* xb = x1i + (long)b * E_TOT * 256;

    if (tid < 256) {
        int e = tid >> 2, s = tid & 3;
        int eg = e0 + e;
        nidx[e][s] = (eg < E_TOT) ? gemm[((long)b * E_TOT + eg) * 4 + s] : 0;
    }
    __syncthreads();                       // nidx ready

    // task coords: 2048 h8-slots = 64 edges x 32 (branch*16 + c8); 4/thread
    int te[4], tc[4], tslot[4];
#pragma unroll
    for (int t = 0; t < 4; ++t) {
        int q = t * 512 + tid;
        te[t] = q >> 5; tc[t] = q & 31;
        tslot[t] = (te[t] * 16 + (tc[t] & 15)) ^ (te[t] & 7);
    }

    // ---- ph1: stage self; issue P1 (f1,f3) loads to regs
#pragma unroll
    for (int t = 0; t < 4; ++t) {
        int eg = e0 + te[t];
        int se = (eg < E_TOT) ? eg : 0;
        h8 v = *(const h8*)(xb + (long)se * 256 + tc[t] * 8);
        ((tc[t] >> 4) ? B1 : B0)[tslot[t]] = v;
    }
    h8 rA[4], rB[4];
#pragma unroll
    for (int t = 0; t < 4; ++t) {
        int na = nidx[te[t]][0], nb = nidx[te[t]][2];
        rA[t] = *(const h8*)(xb + (long)na * 256 + tc[t] * 8);
        rB[t] = *(const h8*)(xb + (long)nb * 256 + tc[t] * 8);
    }
    __syncthreads();

    f32x4 acc[4][2];
#pragma unroll
    for (int mt = 0; mt < 4; ++mt)
#pragma unroll
        for (int nt = 0; nt < 2; ++nt)
#pragma unroll
            for (int j = 0; j < 4; ++j) acc[mt][nt][j] = 0.f;

    const half_t* wt = war + (br ? OFF_WTP2 : OFF_WTE2);
    auto chunk = [&](const h8* bufE, const h8* bufP, int s) {
        const h8* buf = br ? bufP : bufE;
#pragma unroll
        for (int ks = 0; ks < 4; ++ks) {
            h8 bw0 = *(const h8*)(wt + ((long)(o0 + l15) * 5 + s) * 128 + ks * 32 + kg * 8);
            h8 bw1 = *(const h8*)(wt + ((long)(o0 + 16 + l15) * 5 + s) * 128 + ks * 32 + kg * 8);
#pragma unroll
            for (int mt = 0; mt < 4; ++mt) {
                int row = mt * 16 + l15;
                h8 a = buf[row * 16 + ((ks * 4 + kg) ^ (row & 7))];
                acc[mt][0] = __builtin_amdgcn_mfma_f32_16x16x32_f16(a, bw0, acc[mt][0], 0, 0, 0);
                acc[mt][1] = __builtin_amdgcn_mfma_f32_16x16x32_f16(a, bw1, acc[mt][1], 0, 0, 0);
            }
        }
    };

    // ---- ph2: compute s0 (loads land underneath)
    chunk(B0, B1, 0);
    __syncthreads();

    // ---- ph3: write P1 sum/diff; issue P2 (f2,f4)
#pragma unroll
    for (int t = 0; t < 4; ++t) {
        h8 sv = rA[t] + rB[t];
        h8 dv = habs8(rA[t] - rB[t]);
        if (tc[t] >> 4) { B3[tslot[t]] = sv; B1[tslot[t]] = dv; }
        else            { B2[tslot[t]] = sv; B0[tslot[t]] = dv; }
    }
#pragma unroll
    for (int t = 0; t < 4; ++t) {
        int na = nidx[te[t]][1], nb = nidx[te[t]][3];
        rA[t] = *(const h8*)(xb + (long)na * 256 + tc[t] * 8);
        rB[t] = *(const h8*)(xb + (long)nb * 256 + tc[t] * 8);
    }
    __syncthreads();

    // ---- ph4: compute s1 (sums), s3 (diffs)
    chunk(B2, B3, 1);
    chunk(B0, B1, 3);
    __syncthreads();

    // ---- ph5: write P2 sum/diff
#pragma unroll
    for (int t = 0; t < 4; ++t) {
        h8 sv = rA[t] + rB[t];
        h8 dv = habs8(rA[t] - rB[t]);
        if (tc[t] >> 4) { B3[tslot[t]] = sv; B1[tslot[t]] = dv; }
        else            { B2[tslot[t]] = sv; B0[tslot[t]] = dv; }
    }
    __syncthreads();

    // ---- ph6: compute s2, s4
    chunk(B2, B3, 2);
    chunk(B0, B1, 4);

    // ---- epilogue: bias, store, stats partials
    const float* bias = br ? bp : be;
    half_t* yb = (br ? tmpp : tmpe) + (long)b * E_TOT * 128;
    float* part = br ? partp : parte;
    float bv0 = bias[o0 + l15], bv1 = bias[o0 + 16 + l15];
    float s1a = 0.f, s2a = 0.f, s1b = 0.f, s2b = 0.f;
#pragma unroll
    for (int mt = 0; mt < 4; ++mt) {
        int ebase = e0 + mt * 16 + (kg << 2);
#pragma unroll
        for (int j = 0; j < 4; ++j) {
            if (ebase + j < E_TOT) {
                float v0 = acc[mt][0][j] + bv0;
                float v1 = acc[mt][1][j] + bv1;
                yb[(long)(ebase + j) * 128 + o0 + l15]      = (half_t)v0;
                yb[(long)(ebase + j) * 128 + o0 + 16 + l15] = (half_t)v1;
                s1a += v0; s2a += v0 * v0;
                s1b += v1; s2b += v1 * v1;
            }
        }
    }
    s1a += __shfl_xor(s1a, 16); s1a += __shfl_xor(s1a, 32);
    s2a += __shfl_xor(s2a, 16); s2a += __shfl_xor(s2a, 32);
    s1b += __shfl_xor(s1b, 16); s1b += __shfl_xor(s1b, 32);
    s2b += __shfl_xor(s2b, 16); s2b += __shfl_xor(s2b, 32);
    if (lane < 16) {
        long pb = ((long)b * NBLK + blockIdx.x) * 128;
        part[(pb + o0 + lane) * 2 + 0]      = s1a;
        part[(pb + o0 + lane) * 2 + 1]      = s2a;
        part[(pb + o0 + 16 + lane) * 2 + 0] = s1b;
        part[(pb + o0 + 16 + lane) * 2 + 1] = s2b;
    }
}

// ---------------------------------------------------------------------------
// decoder heads A+B merged: shared xall gather, 6-phase pipeline.
// waves 0-3: head A (o-slices of 32); waves 4-7: head B.
// ---------------------------------------------------------------------------
__global__ __launch_bounds__(512, 4)
void heads2_k(const half_t* __restrict__ xall, const int* __restrict__ gemm,
              const half_t* __restrict__ war,
              const float* __restrict__ bal, const float* __restrict__ bbl,
              const float* __restrict__ bat, const float* __restrict__ bbt,
              half_t* __restrict__ xa2, half_t* __restrict__ xb2)
{
    __shared__ h8 C0[512], C1[512], C2[512];
    __shared__ int nidx[64][4];

    const int tid  = threadIdx.x;
    const int b    = blockIdx.y;
    const int e0   = blockIdx.x * TILE_E;
    const int lane = tid & 63;
    const int wv   = tid >> 6;
    const int hd   = wv >> 2;
    const int o0   = (wv & 3) * 32;
    const int l15  = lane & 15;
    const int kg   = lane >> 4;

    const half_t* xb = xall + (long)b * E_TOT * 64;

    if (tid < 256) {
        int e = tid >> 2, s = tid & 3;
        int eg = e0 + e;
        nidx[e][s] = (eg < E_TOT) ? gemm[((long)b * E_TOT + eg) * 4 + s] : 0;
    }
    __syncthreads();

    const int te = tid >> 3, tc = tid & 7;            // 512 tasks, 1/thread
    const int tslot = (te * 8 + tc) ^ (te & 7);

    { // ph1: stage self; issue P1
        int eg = e0 + te;
        int se = (eg < E_TOT) ? eg : 0;
        C0[tslot] = *(const h8*)(xb + (long)se * 64 + tc * 8);
    }
    h8 rA, rB;
    {
        int na = nidx[te][0], nb = nidx[te][2];
        rA = *(const h8*)(xb + (long)na * 64 + tc * 8);
        rB = *(const h8*)(xb + (long)nb * 64 + tc * 8);
    }
    __syncthreads();

    f32x4 acc[4][2];
#pragma unroll
    for (int mt = 0; mt < 4; ++mt)
#pragma unroll
        for (int nt = 0; nt < 2; ++nt)
#pragma unroll
            for (int j = 0; j < 4; ++j) acc[mt][nt][j] = 0.f;

    const half_t* wt = war + (hd ? OFF_WHB : OFF_WHA);
    auto chunk = [&](const h8* buf, int s) {
#pragma unroll
        for (int ks = 0; ks < 2; ++ks) {
            h8 bw0 = *(const h8*)(wt + ((long)(o0 + l15) * 5 + s) * 64 + ks * 32 + kg * 8);
            h8 bw1 = *(const h8*)(wt + ((long)(o0 + 16 + l15) * 5 + s) * 64 + ks * 32 + kg * 8);
#pragma unroll
            for (int mt = 0; mt < 4; ++mt) {
                int row = mt * 16 + l15;
                h8 a = buf[row * 8 + ((ks * 4 + kg) ^ (row & 7))];
                acc[mt][0] = __builtin_amdgcn_mfma_f32_16x16x32_f16(a, bw0, acc[mt][0], 0, 0, 0);
                acc[mt][1] = __builtin_amdgcn_mfma_f32_16x16x32_f16(a, bw1, acc[mt][1], 0, 0, 0);
            }
        }
    };

    chunk(C0, 0);
    __syncthreads();
    { // ph3
        C1[tslot] = rA + rB;
        C2[tslot] = habs8(rA - rB);
        int na = nidx[te][1], nb = nidx[te][3];
        rA = *(const h8*)(xb + (long)na * 64 + tc * 8);
        rB = *(const h8*)(xb + (long)nb * 64 + tc * 8);
    }
    __syncthreads();
    chunk(C1, 1);
    chunk(C2, 3);
    __syncthreads();
    { // ph5
        C1[tslot] = rA + rB;
        C2[tslot] = habs8(rA - rB);
    }
    __syncthreads();
    chunk(C1, 2);
    chunk(C2, 4);

    half_t* yb = (hd ? xb2 : xa2) + (long)b * E_TOT * 128;
    float bv[2];
#pragma unroll
    for (int nt = 0; nt < 2; ++nt) {
        int o = o0 + nt * 16 + l15;
        bv[nt] = (o < 64) ? (hd ? bbl[o] : bal[o]) : (hd ? bbt[o - 64] : bat[o - 64]);
    }
#pragma unroll
    for (int mt = 0; mt < 4; ++mt) {
        int ebase = e0 + mt * 16 + (kg << 2);
#pragma unroll
        for (int j = 0; j < 4; ++j) {
            if (ebase + j < E_TOT) {
#pragma unroll
                for (int nt = 0; nt < 2; ++nt)
                    yb[(long)(ebase + j) * 128 + o0 + nt * 16 + l15] =
                        (half_t)(acc[mt][nt][j] + bv[nt]);
            }
        }
    }
}

// ---------------------------------------------------------------------------
// gates: 1x1 conv C=128 -> O=128, both via blockIdx.y, 8 waves, stats (as R5)
// ---------------------------------------------------------------------------
__global__ __launch_bounds__(512)
void gates_k(const half_t* __restrict__ xa2, const half_t* __restrict__ xb2,
             const half_t* __restrict__ war,
             const float* __restrict__ baf, const float* __restrict__ bbf,
             half_t* __restrict__ tmpe, half_t* __restrict__ tmpp,
             float* __restrict__ parte, float* __restrict__ partp)
{
    __shared__ h8 Gl[64 * 16];

    const int tid  = threadIdx.x;
    const int br   = blockIdx.y;
    const int b    = blockIdx.z;
    const int e0   = blockIdx.x * TILE_E;
    const int lane = tid & 63;
    const int wv   = tid >> 6;
    const int l15  = lane & 15;
    const int kg   = lane >> 4;
    const int o0   = wv * 16;

    const half_t* xb = (br ? xb2 : xa2) + (long)b * E_TOT * 128;
    const half_t* wt = war + (br ? OFF_WTBF : OFF_WTAF);

#pragma unroll
    for (int t = 0; t < 2; ++t) {
        int q = t * 512 + tid;
        int e = q >> 4, c8 = q & 15;
        int eg = e0 + e;
        int se = (eg < E_TOT) ? eg : 0;
        Gl[(e * 16 + c8) ^ (e & 7)] = *(const h8*)(xb + (long)se * 128 + c8 * 8);
    }
    __syncthreads();

    f32x4 acc[4];
#pragma unroll
    for (int mt = 0; mt < 4; ++mt)
#pragma unroll
        for (int j = 0; j < 4; ++j) acc[mt][j] = 0.f;

#pragma unroll
    for (int ks = 0; ks < 4; ++ks) {
        h8 bw = *(const h8*)(wt + (long)(o0 + l15) * 128 + ks * 32 + kg * 8);
#pragma unroll
        for (int mt = 0; mt < 4; ++mt) {
            int row = mt * 16 + l15;
            h8 a = Gl[row * 16 + ((ks * 4 + kg) ^ (row & 7))];
            acc[mt] = __builtin_amdgcn_mfma_f32_16x16x32_f16(a, bw, acc[mt], 0, 0, 0);
        }
    }

    const float* bias = br ? bbf : baf;
    half_t* yb = (br ? tmpp : tmpe) + (long)b * E_TOT * 128;
    float* part = br ? partp : parte;
    float bv = bias[o0 + l15];
    float s1 = 0.f, s2 = 0.f;
#pragma unroll
    for (int mt = 0; mt < 4; ++mt) {
        int ebase = e0 + mt * 16 + (kg << 2);
#pragma unroll
        for (int j = 0; j < 4; ++j) {
            if (ebase + j < E_TOT) {
                float v = acc[mt][j] + bv;
                yb[(long)(ebase + j) * 128 + o0 + l15] = (half_t)v;
                s1 += v; s2 += v * v;
            }
        }
    }
    s1 += __shfl_xor(s1, 16); s1 += __shfl_xor(s1, 32);
    s2 += __shfl_xor(s2, 16); s2 += __shfl_xor(s2, 32);
    if (lane < 16) {
        long pb = ((long)b * NBLK + blockIdx.x) * 128;
        part[(pb + o0 + lane) * 2 + 0] = s1;
        part[(pb + o0 + lane) * 2 + 1] = s2;
    }
}

// ---------------------------------------------------------------------------
// x_all: 1x1 conv C=128 -> O=32, both halves via blockIdx.y (as R5)
// ---------------------------------------------------------------------------
__global__ __launch_bounds__(256)
void xall_k(const half_t* __restrict__ x2e, const half_t* __restrict__ x2p,
            const half_t* __restrict__ war,
            const float* __restrict__ ba, const float* __restrict__ bb,
            half_t* __restrict__ xall)
{
    __shared__ h8 Gl[64 * 16];

    const int tid  = threadIdx.x;
    const int br   = blockIdx.y;
    const int b    = blockIdx.z;
    const int e0   = blockIdx.x * TILE_E;
    const int lane = tid & 63;
    const int wv   = tid >> 6;
    const int l15  = lane & 15;
    const int kg   = lane >> 4;
    const int eoff = wv * 16;

    const half_t* xb = (br ? x2p : x2e) + (long)b * E_TOT * 128;
    const half_t* wt = war + (br ? OFF_WTB : OFF_WTA);

#pragma unroll
    for (int t = 0; t < 4; ++t) {
        int q = t * 256 + tid;
        int e = q >> 4, c8 = q & 15;
        int eg = e0 + e;
        int se = (eg < E_TOT) ? eg : 0;
        Gl[(e * 16 + c8) ^ (e & 7)] = *(const h8*)(xb + (long)se * 128 + c8 * 8);
    }
    __syncthreads();

    f32x4 acc[2];
#pragma unroll
    for (int nt = 0; nt < 2; ++nt)
#pragma unroll
        for (int j = 0; j < 4; ++j) acc[nt][j] = 0.f;

#pragma unroll
    for (int ks = 0; ks < 4; ++ks) {
        h8 bw[2];
#pragma unroll
        for (int nt = 0; nt < 2; ++nt)
            bw[nt] = *(const h8*)(wt + (long)(nt * 16 + l15) * 128 + ks * 32 + kg * 8);
        int row = eoff + l15;
        h8 a = Gl[row * 16 + ((ks * 4 + kg) ^ (row & 7))];
#pragma unroll
        for (int nt = 0; nt < 2; ++nt)
            acc[nt] = __builtin_amdgcn_mfma_f32_16x16x32_f16(a, bw[nt], acc[nt], 0, 0, 0);
    }

    const float* bias = br ? bb : ba;
    half_t* yb = xall + (long)b * E_TOT * 64;
    int oOff = br * 32;
#pragma unroll
    for (int nt = 0; nt < 2; ++nt) {
        float bv = bias[nt * 16 + l15];
        int ebase = e0 + eoff + (kg << 2);
#pragma unroll
        for (int j = 0; j < 4; ++j) {
            if (ebase + j < E_TOT)
                yb[(long)(ebase + j) * 64 + oOff + nt * 16 + l15] = (half_t)(acc[nt][j] + bv);
        }
    }
}

// ---------------------------------------------------------------------------
// stats finalize, both branch buffers: grid 512 = (br, b, o)
// ---------------------------------------------------------------------------
__global__ __launch_bounds__(256)
void stats2_k(const float* __restrict__ parte, const float* __restrict__ partp,
              float* __restrict__ statse, float* __restrict__ statsp)
{
    int g = blockIdx.x;
    int br = g >> 8, rem = g & 255, b = rem >> 7, o = rem & 127;
    const float* part = br ? partp : parte;
    float* stats = br ? statsp : statse;
    int tid = threadIdx.x;
    float s1 = 0.f, s2 = 0.f;
    for (int k = tid; k < NBLK; k += 256) {
        long base = (((long)b * NBLK + k) * 128 + o) * 2;
        s1 += part[base];
        s2 += part[base + 1];
    }
#pragma unroll
    for (int d = 1; d < 64; d <<= 1) {
        s1 += __shfl_xor(s1, d);
        s2 += __shfl_xor(s2, d);
    }
    __shared__ float r1[4], r2[4];
    int wv = tid >> 6;
    if ((tid & 63) == 0) { r1[wv] = s1; r2[wv] = s2; }
    __syncthreads();
    if (tid == 0) {
        s1 = r1[0] + r1[1] + r1[2] + r1[3];
        s2 = r2[0] + r2[1] + r2[2] + r2[3];
        float mean = s1 / (float)E_TOT;
        float var  = s2 / (float)E_TOT - mean * mean;
        var = fmaxf(var, 0.f);
        stats[(b * 128 + o) * 2 + 0] = mean;
        stats[(b * 128 + o) * 2 + 1] = rsqrtf(var + 1e-5f);
    }
}

// ---------------------------------------------------------------------------
// x1 = relu(inorm(tmp)), both branches, writing INTERLEAVED x1i [b][E][2][128]
// ---------------------------------------------------------------------------
__global__ __launch_bounds__(256)
void norm_act2_k(const half_t* __restrict__ tmpe, const half_t* __restrict__ tmpp,
                 const float* __restrict__ statse, const float* __restrict__ statsp,
                 half_t* __restrict__ x1i)
{
    const long PER = (long)B_TOT * E_TOT * 16;   // h8 units per branch
    long q = (long)blockIdx.x * 256 + threadIdx.x;
    if (q >= 2 * PER) return;
    int br = (q >= PER);
    q -= (long)br * PER;
    const half_t* src = br ? tmpp : tmpe;
    const float* stats = br ? statsp : statse;
    long idx = q * 8;
    int c = (int)(idx & 127);
    long be = idx >> 7;
    int b = (int)(be / E_TOT);
    int e = (int)(be % E_TOT);
    h8 v = *(const h8*)&src[idx];
    h8 r;
#pragma unroll
    for (int j = 0; j < 8; ++j) {
        float2 st = *(const float2*)&stats[(b * 128 + c + j) * 2];
        float t = ((float)v[j] - st.x) * st.y;
        r[j] = (half_t)fmaxf(t, 0.f);
    }
    *(h8*)&x1i[((long)b * E_TOT + e) * 256 + br * 128 + c] = r;
}

// ---------------------------------------------------------------------------
// x2 = relu(inorm(tmp)+x1i): f32 channel-major out section + f16 copy.
// residual read from interleaved x1i. blockIdx.y = br*4 + cg.
// ---------------------------------------------------------------------------
__global__ __launch_bounds__(256)
void normres2_k(const half_t* __restrict__ tmpe, const half_t* __restrict__ tmpp,
                const half_t* __restrict__ x1i,
                const float* __restrict__ statse, const float* __restrict__ statsp,
                float* __restrict__ outb,
                half_t* __restrict__ x2e, half_t* __restrict__ x2p)
{
    __shared__ float T[32 * 68];
    int br = blockIdx.y >> 2, cg = blockIdx.y & 3;
    int b = blockIdx.z;
    int e0 = blockIdx.x * 64;
    int tid = threadIdx.x;
    const half_t* xin = br ? tmpp : tmpe;
    const float* stats = br ? statsp : statse;
    half_t* x2b = br ? x2p : x2e;
    int sect = br * 128;
#pragma unroll
    for (int i = 0; i < 2; ++i) {
        int q = tid + i * 256;
        int e = q >> 3, cq = q & 7;
        int eg = e0 + e;
        int se = (eg < E_TOT) ? eg : (E_TOT - 1);
        int c = cg * 32 + cq * 4;
        long base = ((long)b * E_TOT + se) * 128 + c;
        h4 v4 = *(const h4*)&xin[base];
        h4 r4 = *(const h4*)&x1i[((long)b * E_TOT + se) * 256 + br * 128 + c];
        h4 o4;
#pragma unroll
        for (int j = 0; j < 4; ++j) {
            float2 st = *(const float2*)&stats[(b * 128 + c + j) * 2];
            float t = ((float)v4[j] - st.x) * st.y + (float)r4[j];
            t = fmaxf(t, 0.f);
            T[(cq * 4 + j) * 68 + e] = t;
            o4[j] = (half_t)t;
        }
        if (eg < E_TOT) *(h4*)&x2b[base] = o4;
    }
    __syncthreads();
#pragma unroll
    for (int i = 0; i < 2; ++i) {
        int q = tid + i * 256;
        int cl = q >> 4, eq = q & 15;
        int e4 = e0 + eq * 4;
        int cglob = sect + cg * 32 + cl;
        float4 v = *(const float4*)&T[cl * 68 + eq * 4];
        long obase = ((long)b * 384 + cglob) * E_TOT + e4;
        if (e4 + 3 < E_TOT) {
            *(float4*)&outb[obase] = v;
        } else {
            const float* vp = &v.x;
            for (int j = 0; j < 4; ++j)
                if (e4 + j < E_TOT) outb[obase + j] = vp[j];
        }
    }
}

// ---------------------------------------------------------------------------
// fused gates-norm + softmax2 + aggregate (as R5)
// ---------------------------------------------------------------------------
__global__ __launch_bounds__(256)
void gate_agg2_k(const half_t* __restrict__ tA, const half_t* __restrict__ tB,
                 const float* __restrict__ statsA, const float* __restrict__ statsB,
                 const half_t* __restrict__ x2e, const half_t* __restrict__ x2p,
                 float* __restrict__ outb)
{
    __shared__ float T[32 * 68];
    int b = blockIdx.z, cg = blockIdx.y;
    int e0 = blockIdx.x * 64;
    int tid = threadIdx.x;
#pragma unroll
    for (int i = 0; i < 2; ++i) {
        int q = tid + i * 256;
        int e = q >> 3, cq = q & 7;
        int eg = e0 + e;
        int se = (eg < E_TOT) ? eg : (E_TOT - 1);
        int c = cg * 32 + cq * 4;
        long base = ((long)b * E_TOT + se) * 128 + c;
        h4 a4 = *(const h4*)&tA[base];
        h4 b4 = *(const h4*)&tB[base];
        h4 xe4 = *(const h4*)&x2e[base];
        h4 xp4 = *(const h4*)&x2p[base];
#pragma unroll
        for (int j = 0; j < 4; ++j) {
            float2 sa = *(const float2*)&statsA[(b * 128 + c + j) * 2];
            float2 sb = *(const float2*)&statsB[(b * 128 + c + j) * 2];
            float na = sigmoidf_(((float)a4[j] - sa.x) * sa.y);
            float nb = sigmoidf_(((float)b4[j] - sb.x) * sb.y);
            float s = sigmoidf_(na - nb);
            T[(cq * 4 + j) * 68 + e] = (float)xe4[j] * s + (float)xp4[j] * (1.f - s);
        }
    }
    __syncthreads();
#pragma unroll
    for (int i = 0; i < 2; ++i) {
        int q = tid + i * 256;
        int cl = q >> 4, eq = q & 15;
        int e4 = e0 + eq * 4;
        int cglob = cg * 32 + cl;
        float4 v = *(const float4*)&T[cl * 68 + eq * 4];
        long ab = ((long)b * 384 + 256 + cglob) * E_TOT + e4;
        if (e4 + 3 < E_TOT) {
            *(float4*)&outb[ab] = v;
        } else {
            const float* vp = &v.x;
            for (int j = 0; j < 4; ++j)
                if (e4 + j < E_TOT) outb[ab + j] = vp[j];
        }
    }
}

// ---------------------------------------------------------------------------
extern "C" void kernel_launch(void* const* d_in, const int* in_sizes, int n_in,
                              void* d_out, int out_size, void* d_ws, size_t ws_size,
                              hipStream_t stream)
{
    const float* fe   = (const float*)d_in[0];
    const int*   gemm = (const int*)  d_in[1];
    const float* w_e1 = (const float*)d_in[2];  const float* b_e1 = (const float*)d_in[3];
    const float* w_p1 = (const float*)d_in[4];  const float* b_p1 = (const float*)d_in[5];
    const float* w_e2 = (const float*)d_in[6];  const float* b_e2 = (const float*)d_in[7];
    const float* w_p2 = (const float*)d_in[8];  const float* b_p2 = (const float*)d_in[9];
    const float* wa   = (const float*)d_in[10]; const float* ba   = (const float*)d_in[11];
    const float* wb   = (const float*)d_in[12]; const float* bb   = (const float*)d_in[13];
    const float* wal  = (const float*)d_in[14]; const float* bal  = (const float*)d_in[15];
    const float* wbl  = (const float*)d_in[16]; const float* bbl  = (const float*)d_in[17];
    const float* wat  = (const float*)d_in[18]; const float* bat  = (const float*)d_in[19];
    const float* wbt  = (const float*)d_in[20]; const float* bbt  = (const float*)d_in[21];
    const float* waf  = (const float*)d_in[22]; const float* baf  = (const float*)d_in[23];
    const float* wbf  = (const float*)d_in[24]; const float* bbf  = (const float*)d_in[25];
    float* out = (float*)d_out;

    const long EB = (long)E_TOT;

    char* wp = (char*)d_ws;
    auto alloc = [&](size_t bytes) -> void* {
        void* r = (void*)wp;
        wp += (bytes + 255) & ~(size_t)255;
        return r;
    };
    float*  FET    = (float*)alloc((size_t)B_TOT * EB * 8 * 4);
    half_t* TMP_E  = (half_t*)alloc((size_t)B_TOT * EB * 128 * 2);
    half_t* TMP_P  = (half_t*)alloc((size_t)B_TOT * EB * 128 * 2);
    half_t* X1I    = (half_t*)alloc((size_t)B_TOT * EB * 256 * 2);   // interleaved; later XA2/XB2
    half_t* X2E    = (half_t*)alloc((size_t)B_TOT * EB * 128 * 2);
    half_t* X2P    = (half_t*)alloc((size_t)B_TOT * EB * 128 * 2);
    half_t* XALL   = (half_t*)alloc((size_t)B_TOT * EB * 64 * 2);
    float*  PART_E = (float*)alloc((size_t)B_TOT * NBLK * 128 * 2 * 4);
    float*  PART_P = (float*)alloc((size_t)B_TOT * NBLK * 128 * 2 * 4);
    float*  STATSE = (float*)alloc((size_t)B_TOT * 128 * 2 * 4);
    float*  STATSP = (float*)alloc((size_t)B_TOT * 128 * 2 * 4);
    half_t* WAR    = (half_t*)alloc((size_t)WARENA_N * 2);

    if ((size_t)(wp - (char*)d_ws) > ws_size) {
        fprintf(stderr, "kernel_launch: ws too small (%zu < %zu)\n",
                ws_size, (size_t)(wp - (char*)d_ws));
        return;
    }

    // X1I dead after normres2; reuse for decoder-head outputs
    half_t* XA2 = X1I;
    half_t* XB2 = X1I + (size_t)B_TOT * EB * 128;

    dim3 blk256(256), blk512(512);
    dim3 gI(NBLK, B_TOT);
    dim3 gE2(NBLK, 2, B_TOT);
    dim3 gT((E_TOT + 255) / 256, 1, B_TOT);
    dim3 gN8(NBLK, 8, B_TOT);
    dim3 gN4(NBLK, 4, B_TOT);
    int gA2 = (int)((2 * (long)B_TOT * EB * 16 + 255) / 256);

    // 1-2: prep
    wprep_k<<<dim3(320, 10, 1), blk256, 0, stream>>>(WAR,
        w_e1, w_p1, w_e2, w_p2, wat, wbt, wa, wb, wal, wbl, waf, wbf);
    transpose_in_k<<<gT, blk256, 0, stream>>>(fe, FET);

    // 3-5: layer 1 (both branches), norm -> interleaved x1i
    mesh1_both_k<<<gI, blk512, 0, stream>>>(FET, gemm, WAR, b_e1, b_p1,
        TMP_E, TMP_P, PART_E, PART_P);
    stats2_k<<<512, blk256, 0, stream>>>(PART_E, PART_P, STATSE, STATSP);
    norm_act2_k<<<gA2, blk256, 0, stream>>>(TMP_E, TMP_P, STATSE, STATSP, X1I);

    // 6-8: layer 2 (interleaved, pipelined) + norm/res
    mesh2i_k<<<gI, blk512, 0, stream>>>(X1I, gemm, WAR, b_e2, b_p2,
        TMP_E, TMP_P, PART_E, PART_P);
    stats2_k<<<512, blk256, 0, stream>>>(PART_E, PART_P, STATSE, STATSP);
    normres2_k<<<gN8, blk256, 0, stream>>>(TMP_E, TMP_P, X1I, STATSE, STATSP,
        out, X2E, X2P);

    // 9: x_all
    xall_k<<<gE2, blk256, 0, stream>>>(X2E, X2P, WAR, ba, bb, XALL);

    // 10: decoder heads (A+B merged, shared gather)
    heads2_k<<<gI, blk512, 0, stream>>>(XALL, gemm, WAR, bal, bbl, bat, bbt, XA2, XB2);

    // 11-13: gates + aggregate
    gates_k<<<gE2, blk512, 0, stream>>>(XA2, XB2, WAR, baf, bbf,
        TMP_E, TMP_P, PART_E, PART_P);
    stats2_k<<<512, blk256, 0, stream>>>(PART_E, PART_P, STATSE, STATSP);
    gate_agg2_k<<<gN4, blk256, 0, stream>>>(TMP_E, TMP_P, STATSE, STATSP,
        X2E, X2P, out);
}

// Round 7
// 370.406 us; speedup vs baseline: 1.0144x; 1.0144x over previous
//
#include <hip/hip_runtime.h>
#include <cstdio>
#include <math.h>

// ---------------------------------------------------------------------------
// MeshEncoderDecoder — round 7: revert mesh2 to R5 one-branch-per-block
// structure (33 KB LDS) + T14 register-prefetch of pair gathers.
// ---------------------------------------------------------------------------

#define E_TOT 50000
#define B_TOT 2
#define TILE_E 64
#define NBLK ((E_TOT + TILE_E - 1) / TILE_E)   // 782

typedef _Float16 half_t;
typedef __attribute__((ext_vector_type(4))) _Float16 h4;
typedef __attribute__((ext_vector_type(8))) _Float16 h8;
typedef __attribute__((ext_vector_type(4))) float f32x4;

__device__ __forceinline__ float sigmoidf_(float x) {
    return 1.0f / (1.0f + __expf(-x));
}
__device__ __forceinline__ h8 habs8(h8 x) {
    union { h8 h; unsigned int u[4]; } v;
    v.h = x;
#pragma unroll
    for (int i = 0; i < 4; ++i) v.u[i] &= 0x7FFF7FFFu;
    return v.h;
}

// ---------------------------------------------------------------------------
// weight arena offsets (halves)
// ---------------------------------------------------------------------------
#define OFF_W1E   0          // 128*64 (k = s*8+cc, zero-padded)
#define OFF_W1P   8192       // 128*64
#define OFF_WTE2  16384      // 128*5*128
#define OFF_WTP2  98304      // 128*5*128
#define OFF_WHA   180224     // 128*5*64 (o<64: wal in s0; o>=64: wat)
#define OFF_WHB   221184     // 128*5*64
#define OFF_WTA   262144     // 32*128
#define OFF_WTB   266240     // 32*128
#define OFF_WTAF  270336     // 128*128
#define OFF_WTBF  286720     // 128*128
#define WARENA_N  303104

__global__ __launch_bounds__(256)
void wprep_k(half_t* __restrict__ wa_,
             const float* __restrict__ w_e1, const float* __restrict__ w_p1,
             const float* __restrict__ w_e2, const float* __restrict__ w_p2,
             const float* __restrict__ wat,  const float* __restrict__ wbt,
             const float* __restrict__ wa,   const float* __restrict__ wb,
             const float* __restrict__ wal,  const float* __restrict__ wbl,
             const float* __restrict__ waf,  const float* __restrict__ wbf)
{
    int idx = blockIdx.x * 256 + threadIdx.x;
    switch (blockIdx.y) {
    case 0: if (idx < 8192) { int o = idx >> 6, k = idx & 63, s = k >> 3, cc = k & 7;
            float v = (s < 5 && cc < 5) ? w_e1[o * 25 + cc * 5 + s] : 0.f;
            wa_[OFF_W1E + idx] = (half_t)v; } break;
    case 1: if (idx < 8192) { int o = idx >> 6, k = idx & 63, s = k >> 3, cc = k & 7;
            float v = (s < 5 && cc >= 5) ? w_p1[o * 15 + (cc - 5) * 5 + s] : 0.f;
            wa_[OFF_W1P + idx] = (half_t)v; } break;
    case 2: if (idx < 81920) { int o = idx / 640, r = idx % 640, s = r >> 7, c = r & 127;
            wa_[OFF_WTE2 + idx] = (half_t)w_e2[(o * 128 + c) * 5 + s]; } break;
    case 3: if (idx < 81920) { int o = idx / 640, r = idx % 640, s = r >> 7, c = r & 127;
            wa_[OFF_WTP2 + idx] = (half_t)w_p2[(o * 128 + c) * 5 + s]; } break;
    case 4: if (idx < 40960) { int o = idx / 320, r = idx % 320, s = r >> 6, c = r & 63;
            float v = (o < 64) ? (s == 0 ? wal[o * 64 + c] : 0.f)
                               : wat[((o - 64) * 64 + c) * 5 + s];
            wa_[OFF_WHA + idx] = (half_t)v; } break;
    case 5: if (idx < 40960) { int o = idx / 320, r = idx % 320, s = r >> 6, c = r & 63;
            float v = (o < 64) ? (s == 0 ? wbl[o * 64 + c] : 0.f)
                               : wbt[((o - 64) * 64 + c) * 5 + s];
            wa_[OFF_WHB + idx] = (half_t)v; } break;
    case 6: if (idx < 4096)  wa_[OFF_WTA  + idx] = (half_t)wa[idx];  break;
    case 7: if (idx < 4096)  wa_[OFF_WTB  + idx] = (half_t)wb[idx];  break;
    case 8: if (idx < 16384) wa_[OFF_WTAF + idx] = (half_t)waf[idx]; break;
    case 9: if (idx < 16384) wa_[OFF_WTBF + idx] = (half_t)wbf[idx]; break;
    }
}

// ---------------------------------------------------------------------------
// transpose fe (b, 8, E) -> fe_t (b, E, 8) f32
// ---------------------------------------------------------------------------
__global__ __launch_bounds__(256)
void transpose_in_k(const float* __restrict__ fe, float* __restrict__ fet)
{
    int b = blockIdx.z;
    int e = blockIdx.x * 256 + threadIdx.x;
    if (e >= E_TOT) return;
    float v[8];
#pragma unroll
    for (int c = 0; c < 8; ++c)
        v[c] = fe[((long)b * 8 + c) * E_TOT + e];
    float4* dst = (float4*)&fet[((long)b * E_TOT + e) * 8];
    dst[0] = make_float4(v[0], v[1], v[2], v[3]);
    dst[1] = make_float4(v[4], v[5], v[6], v[7]);
}

// ---------------------------------------------------------------------------
// layer-1 both branches: shared G, K=64, 8 waves (0-3 edge, 4-7 point)
// ---------------------------------------------------------------------------
__global__ __launch_bounds__(512)
void mesh1_both_k(const float* __restrict__ fet, const int* __restrict__ gemm,
                  const half_t* __restrict__ war,
                  const float* __restrict__ be1, const float* __restrict__ bp1,
                  half_t* __restrict__ tmpe, half_t* __restrict__ tmpp,
                  float* __restrict__ parte, float* __restrict__ partp)
{
    __shared__ h8 Gl[64 * 8];
    __shared__ int nidx[64][4];

    const int tid  = threadIdx.x;
    const int b    = blockIdx.y;
    const int e0   = blockIdx.x * TILE_E;
    const int lane = tid & 63;
    const int wv   = tid >> 6;
    const int l15  = lane & 15;
    const int kg   = lane >> 4;
    const int br   = wv >> 2;
    const int o0   = (wv & 3) * 32;

    const float* xb = fet + (long)b * E_TOT * 8;

    if (tid < 256) {
        int e = tid >> 2, s = tid & 3;
        int eg = e0 + e;
        nidx[e][s] = (eg < E_TOT) ? gemm[((long)b * E_TOT + eg) * 4 + s] : 0;
    }
    __syncthreads();

    {
        int e = tid >> 3, g = tid & 7;
        int eg = e0 + e;
        int se = (eg < E_TOT) ? eg : 0;
        h8 r;
        if (g == 0) {
            const float* p = xb + (long)se * 8;
            float4 v0 = *(const float4*)p, v1 = *(const float4*)(p + 4);
            r[0] = (half_t)v0.x; r[1] = (half_t)v0.y; r[2] = (half_t)v0.z; r[3] = (half_t)v0.w;
            r[4] = (half_t)v1.x; r[5] = (half_t)v1.y; r[6] = (half_t)v1.z; r[7] = (half_t)v1.w;
        } else if (g <= 4) {
            int ia = (g == 1 || g == 3) ? 0 : 1;
            const float* pa = xb + (long)nidx[e][ia] * 8;
            const float* pb = xb + (long)nidx[e][ia + 2] * 8;
            float4 a0 = *(const float4*)pa, a1 = *(const float4*)(pa + 4);
            float4 b0 = *(const float4*)pb, b1 = *(const float4*)(pb + 4);
            float aa[8] = {a0.x, a0.y, a0.z, a0.w, a1.x, a1.y, a1.z, a1.w};
            float bb[8] = {b0.x, b0.y, b0.z, b0.w, b1.x, b1.y, b1.z, b1.w};
            if (g <= 2) {
#pragma unroll
                for (int j = 0; j < 8; ++j) r[j] = (half_t)(aa[j] + bb[j]);
            } else {
#pragma unroll
                for (int j = 0; j < 8; ++j) r[j] = (half_t)fabsf(aa[j] - bb[j]);
            }
        } else {
#pragma unroll
            for (int j = 0; j < 8; ++j) r[j] = (half_t)0.f;
        }
        Gl[(e * 8 + g) ^ (e & 7)] = r;
    }
    __syncthreads();

    f32x4 acc[4][2];
#pragma unroll
    for (int mt = 0; mt < 4; ++mt)
#pragma unroll
        for (int nt = 0; nt < 2; ++nt)
#pragma unroll
            for (int j = 0; j < 4; ++j) acc[mt][nt][j] = 0.f;

    const half_t* wt = war + (br ? OFF_W1P : OFF_W1E);
#pragma unroll
    for (int ks = 0; ks < 2; ++ks) {
        h8 bw[2];
#pragma unroll
        for (int nt = 0; nt < 2; ++nt)
            bw[nt] = *(const h8*)(wt + (long)(o0 + nt * 16 + l15) * 64 + ks * 32 + kg * 8);
#pragma unroll
        for (int mt = 0; mt < 4; ++mt) {
            int row = mt * 16 + l15;
            h8 a = Gl[row * 8 + ((ks * 4 + kg) ^ (row & 7))];
#pragma unroll
            for (int nt = 0; nt < 2; ++nt)
                acc[mt][nt] = __builtin_amdgcn_mfma_f32_16x16x32_f16(a, bw[nt], acc[mt][nt], 0, 0, 0);
        }
    }

    const float* bias = br ? bp1 : be1;
    half_t* yb = (br ? tmpp : tmpe) + (long)b * E_TOT * 128;
    float* part = br ? partp : parte;
    float bv[2], s1[2], s2[2];
#pragma unroll
    for (int nt = 0; nt < 2; ++nt) {
        bv[nt] = bias[o0 + nt * 16 + l15];
        s1[nt] = 0.f; s2[nt] = 0.f;
    }
#pragma unroll
    for (int mt = 0; mt < 4; ++mt) {
        int ebase = e0 + mt * 16 + (kg << 2);
#pragma unroll
        for (int j = 0; j < 4; ++j) {
            if (ebase + j < E_TOT) {
#pragma unroll
                for (int nt = 0; nt < 2; ++nt) {
                    float v = acc[mt][nt][j] + bv[nt];
                    yb[(long)(ebase + j) * 128 + o0 + nt * 16 + l15] = (half_t)v;
                    s1[nt] += v; s2[nt] += v * v;
                }
            }
        }
    }
#pragma unroll
    for (int nt = 0; nt < 2; ++nt) {
        s1[nt] += __shfl_xor(s1[nt], 16); s1[nt] += __shfl_xor(s1[nt], 32);
        s2[nt] += __shfl_xor(s2[nt], 16); s2[nt] += __shfl_xor(s2[nt], 32);
    }
    if (lane < 16) {
        long pb = ((long)b * NBLK + blockIdx.x) * 128;
#pragma unroll
        for (int nt = 0; nt < 2; ++nt) {
            part[(pb + o0 + nt * 16 + lane) * 2 + 0] = s1[nt];
            part[(pb + o0 + nt * 16 + lane) * 2 + 1] = s2[nt];
        }
    }
}

// ---------------------------------------------------------------------------
// layer-2 mesh conv: one branch per block (blockIdx.y), 8 waves, 33 KB LDS,
// T14 register-prefetch of pair gathers (pair-1 lands under s0 compute,
// pair-2 under s1+s3 compute).
// ---------------------------------------------------------------------------
__global__ __launch_bounds__(512)
void mesh2p_k(const half_t* __restrict__ x1e, const half_t* __restrict__ x1p,
              const int* __restrict__ gemm, const half_t* __restrict__ war,
              const float* __restrict__ be, const float* __restrict__ bp,
              half_t* __restrict__ tmpe, half_t* __restrict__ tmpp,
              float* __restrict__ parte, float* __restrict__ partp)
{
    __shared__ h8 A[1024];    // 16 KB
    __shared__ h8 Bs[1024];   // 16 KB
    __shared__ int nidx[64][4];

    const int tid  = threadIdx.x;
    const int br   = blockIdx.y;
    const int b    = blockIdx.z;
    const int e0   = blockIdx.x * TILE_E;
    const int lane = tid & 63;
    const int wv   = tid >> 6;
    const int l15  = lane & 15;
    const int kg   = lane >> 4;
    const int o0   = wv * 16;

    const half_t* xb = (br ? x1p : x1e) + (long)b * E_TOT * 128;
    const half_t* wt = war + (br ? OFF_WTP2 : OFF_WTE2);

    if (tid < 256) {
        int e = tid >> 2, s = tid & 3;
        int eg = e0 + e;
        nidx[e][s] = (eg < E_TOT) ? gemm[((long)b * E_TOT + eg) * 4 + s] : 0;
    }
    __syncthreads();                           // nidx ready

    // 1024 16B-slots (64 e x 16 c8), 2 per thread
    int te[2], tc[2], ts[2];
#pragma unroll
    for (int t = 0; t < 2; ++t) {
        int q = t * 512 + tid;
        te[t] = q >> 4; tc[t] = q & 15;
        ts[t] = (te[t] * 16 + tc[t]) ^ (te[t] & 7);
    }

    // self -> LDS A (issued FIRST so its waitcnt doesn't drain the prefetch)
#pragma unroll
    for (int t = 0; t < 2; ++t) {
        int eg = e0 + te[t];
        int se = (eg < E_TOT) ? eg : 0;
        A[ts[t]] = *(const h8*)(xb + (long)se * 128 + tc[t] * 8);
    }
    // pair-1 (f1,f3) prefetch to regs — stays in flight across the barrier
    h8 rA[2], rB[2];
#pragma unroll
    for (int t = 0; t < 2; ++t) {
        rA[t] = *(const h8*)(xb + (long)nidx[te[t]][0] * 128 + tc[t] * 8);
        rB[t] = *(const h8*)(xb + (long)nidx[te[t]][2] * 128 + tc[t] * 8);
    }
    __syncthreads();

    f32x4 acc[4];
#pragma unroll
    for (int mt = 0; mt < 4; ++mt)
#pragma unroll
        for (int j = 0; j < 4; ++j) acc[mt][j] = 0.f;

    auto chunk = [&](const h8* buf, int s) {
#pragma unroll
        for (int ks = 0; ks < 4; ++ks) {
            h8 bw = *(const h8*)(wt + ((long)(o0 + l15) * 5 + s) * 128 + ks * 32 + kg * 8);
#pragma unroll
            for (int mt = 0; mt < 4; ++mt) {
                int row = mt * 16 + l15;
                h8 a = buf[row * 16 + ((ks * 4 + kg) ^ (row & 7))];
                acc[mt] = __builtin_amdgcn_mfma_f32_16x16x32_f16(a, bw, acc[mt], 0, 0, 0);
            }
        }
    };

    chunk(A, 0);                 // pair-1 loads land underneath
    __syncthreads();

    // write pair-1 (sum->Bs, diff->A); prefetch pair-2 (f2,f4)
#pragma unroll
    for (int t = 0; t < 2; ++t) {
        Bs[ts[t]] = rA[t] + rB[t];
        A[ts[t]]  = habs8(rA[t] - rB[t]);
    }
#pragma unroll
    for (int t = 0; t < 2; ++t) {
        rA[t] = *(const h8*)(xb + (long)nidx[te[t]][1] * 128 + tc[t] * 8);
        rB[t] = *(const h8*)(xb + (long)nidx[te[t]][3] * 128 + tc[t] * 8);
    }
    __syncthreads();

    chunk(Bs, 1);                // s1 = f1+f3
    chunk(A, 3);                 // s3 = |f1-f3| ; pair-2 lands underneath
    __syncthreads();

#pragma unroll
    for (int t = 0; t < 2; ++t) {
        Bs[ts[t]] = rA[t] + rB[t];
        A[ts[t]]  = habs8(rA[t] - rB[t]);
    }
    __syncthreads();

    chunk(Bs, 2);                // s2 = f2+f4
    chunk(A, 4);                 // s4 = |f2-f4|

    const float* bias = br ? bp : be;
    half_t* yb = (br ? tmpp : tmpe) + (long)b * E_TOT * 128;
    float* part = br ? partp : parte;
    float bv = bias[o0 + l15];
    float s1 = 0.f, s2 = 0.f;
#pragma unroll
    for (int mt = 0; mt < 4; ++mt) {
        int ebase = e0 + mt * 16 + (kg << 2);
#pragma unroll
        for (int j = 0; j < 4; ++j) {
            if (ebase + j < E_TOT) {
                float v = acc[mt][j] + bv;
                yb[(long)(ebase + j) * 128 + o0 + l15] = (half_t)v;
                s1 += v; s2 += v * v;
            }
        }
    }
    s1 += __shfl_xor(s1, 16); s1 += __shfl_xor(s1, 32);
    s2 += __shfl_xor(s2, 16); s2 += __shfl_xor(s2, 32);
    if (lane < 16) {
        long pb = ((long)b * NBLK + blockIdx.x) * 128;
        part[(pb + o0 + lane) * 2 + 0] = s1;
        part[(pb + o0 + lane) * 2 + 1] = s2;
    }
}

// ---------------------------------------------------------------------------
// decoder heads A+B merged: shared xall gather, T14 pipeline (from R6)
// ---------------------------------------------------------------------------
__global__ __launch_bounds__(512)
void heads2_k(const half_t* __restrict__ xall, const int* __restrict__ gemm,
              const half_t* __restrict__ war,
              const float* __restrict__ bal, const float* __restrict__ bbl,
              const float* __restrict__ bat, const float* __restrict__ bbt,
              half_t* __restrict__ xa2, half_t* __restrict__ xb2)
{
    __shared__ h8 C0[512], C1[512], C2[512];
    __shared__ int nidx[64][4];

    const int tid  = threadIdx.x;
    const int b    = blockIdx.y;
    const int e0   = blockIdx.x * TILE_E;
    const int lane = tid & 63;
    const int wv   = tid >> 6;
    const int hd   = wv >> 2;
    const int o0   = (wv & 3) * 32;
    const int l15  = lane & 15;
    const int kg   = lane >> 4;

    const half_t* xb = xall + (long)b * E_TOT * 64;

    if (tid < 256) {
        int e = tid >> 2, s = tid & 3;
        int eg = e0 + e;
        nidx[e][s] = (eg < E_TOT) ? gemm[((long)b * E_TOT + eg) * 4 + s] : 0;
    }
    __syncthreads();

    const int te = tid >> 3, tc = tid & 7;
    const int tslot = (te * 8 + tc) ^ (te & 7);

    {
        int eg = e0 + te;
        int se = (eg < E_TOT) ? eg : 0;
        C0[tslot] = *(const h8*)(xb + (long)se * 64 + tc * 8);
    }
    h8 rA, rB;
    {
        int na = nidx[te][0], nb = nidx[te][2];
        rA = *(const h8*)(xb + (long)na * 64 + tc * 8);
        rB = *(const h8*)(xb + (long)nb * 64 + tc * 8);
    }
    __syncthreads();

    f32x4 acc[4][2];
#pragma unroll
    for (int mt = 0; mt < 4; ++mt)
#pragma unroll
        for (int nt = 0; nt < 2; ++nt)
#pragma unroll
            for (int j = 0; j < 4; ++j) acc[mt][nt][j] = 0.f;

    const half_t* wt = war + (hd ? OFF_WHB : OFF_WHA);
    auto chunk = [&](const h8* buf, int s) {
#pragma unroll
        for (int ks = 0; ks < 2; ++ks) {
            h8 bw0 = *(const h8*)(wt + ((long)(o0 + l15) * 5 + s) * 64 + ks * 32 + kg * 8);
            h8 bw1 = *(const h8*)(wt + ((long)(o0 + 16 + l15) * 5 + s) * 64 + ks * 32 + kg * 8);
#pragma unroll
            for (int mt = 0; mt < 4; ++mt) {
                int row = mt * 16 + l15;
                h8 a = buf[row * 8 + ((ks * 4 + kg) ^ (row & 7))];
                acc[mt][0] = __builtin_amdgcn_mfma_f32_16x16x32_f16(a, bw0, acc[mt][0], 0, 0, 0);
                acc[mt][1] = __builtin_amdgcn_mfma_f32_16x16x32_f16(a, bw1, acc[mt][1], 0, 0, 0);
            }
        }
    };

    chunk(C0, 0);
    __syncthreads();
    {
        C1[tslot] = rA + rB;
        C2[tslot] = habs8(rA - rB);
        int na = nidx[te][1], nb = nidx[te][3];
        rA = *(const h8*)(xb + (long)na * 64 + tc * 8);
        rB = *(const h8*)(xb + (long)nb * 64 + tc * 8);
    }
    __syncthreads();
    chunk(C1, 1);
    chunk(C2, 3);
    __syncthreads();
    {
        C1[tslot] = rA + rB;
        C2[tslot] = habs8(rA - rB);
    }
    __syncthreads();
    chunk(C1, 2);
    chunk(C2, 4);

    half_t* yb = (hd ? xb2 : xa2) + (long)b * E_TOT * 128;
    float bv[2];
#pragma unroll
    for (int nt = 0; nt < 2; ++nt) {
        int o = o0 + nt * 16 + l15;
        bv[nt] = (o < 64) ? (hd ? bbl[o] : bal[o]) : (hd ? bbt[o - 64] : bat[o - 64]);
    }
#pragma unroll
    for (int mt = 0; mt < 4; ++mt) {
        int ebase = e0 + mt * 16 + (kg << 2);
#pragma unroll
        for (int j = 0; j < 4; ++j) {
            if (ebase + j < E_TOT) {
#pragma unroll
                for (int nt = 0; nt < 2; ++nt)
                    yb[(long)(ebase + j) * 128 + o0 + nt * 16 + l15] =
                        (half_t)(acc[mt][nt][j] + bv[nt]);
            }
        }
    }
}

// ---------------------------------------------------------------------------
// gates: 1x1 conv C=128 -> O=128, both via blockIdx.y, 8 waves, stats
// ---------------------------------------------------------------------------
__global__ __launch_bounds__(512)
void gates_k(const half_t* __restrict__ xa2, const half_t* __restrict__ xb2,
             const half_t* __restrict__ war,
             const float* __restrict__ baf, const float* __restrict__ bbf,
             half_t* __restrict__ tmpe, half_t* __restrict__ tmpp,
             float* __restrict__ parte, float* __restrict__ partp)
{
    __shared__ h8 Gl[64 * 16];

    const int tid  = threadIdx.x;
    const int br   = blockIdx.y;
    const int b    = blockIdx.z;
    const int e0   = blockIdx.x * TILE_E;
    const int lane = tid & 63;
    const int wv   = tid >> 6;
    const int l15  = lane & 15;
    const int kg   = lane >> 4;
    const int o0   = wv * 16;

    const half_t* xb = (br ? xb2 : xa2) + (long)b * E_TOT * 128;
    const half_t* wt = war + (br ? OFF_WTBF : OFF_WTAF);

#pragma unroll
    for (int t = 0; t < 2; ++t) {
        int q = t * 512 + tid;
        int e = q >> 4, c8 = q & 15;
        int eg = e0 + e;
        int se = (eg < E_TOT) ? eg : 0;
        Gl[(e * 16 + c8) ^ (e & 7)] = *(const h8*)(xb + (long)se * 128 + c8 * 8);
    }
    __syncthreads();

    f32x4 acc[4];
#pragma unroll
    for (int mt = 0; mt < 4; ++mt)
#pragma unroll
        for (int j = 0; j < 4; ++j) acc[mt][j] = 0.f;

#pragma unroll
    for (int ks = 0; ks < 4; ++ks) {
        h8 bw = *(const h8*)(wt + (long)(o0 + l15) * 128 + ks * 32 + kg * 8);
#pragma unroll
        for (int mt = 0; mt < 4; ++mt) {
            int row = mt * 16 + l15;
            h8 a = Gl[row * 16 + ((ks * 4 + kg) ^ (row & 7))];
            acc[mt] = __builtin_amdgcn_mfma_f32_16x16x32_f16(a, bw, acc[mt], 0, 0, 0);
        }
    }

    const float* bias = br ? bbf : baf;
    half_t* yb = (br ? tmpp : tmpe) + (long)b * E_TOT * 128;
    float* part = br ? partp : parte;
    float bv = bias[o0 + l15];
    float s1 = 0.f, s2 = 0.f;
#pragma unroll
    for (int mt = 0; mt < 4; ++mt) {
        int ebase = e0 + mt * 16 + (kg << 2);
#pragma unroll
        for (int j = 0; j < 4; ++j) {
            if (ebase + j < E_TOT) {
                float v = acc[mt][j] + bv;
                yb[(long)(ebase + j) * 128 + o0 + l15] = (half_t)v;
                s1 += v; s2 += v * v;
            }
        }
    }
    s1 += __shfl_xor(s1, 16); s1 += __shfl_xor(s1, 32);
    s2 += __shfl_xor(s2, 16); s2 += __shfl_xor(s2, 32);
    if (lane < 16) {
        long pb = ((long)b * NBLK + blockIdx.x) * 128;
        part[(pb + o0 + lane) * 2 + 0] = s1;
        part[(pb + o0 + lane) * 2 + 1] = s2;
    }
}

// ---------------------------------------------------------------------------
// x_all: 1x1 conv C=128 -> O=32, both halves via blockIdx.y
// ---------------------------------------------------------------------------
__global__ __launch_bounds__(256)
void xall_k(const half_t* __restrict__ x2e, const half_t* __restrict__ x2p,
            const half_t* __restrict__ war,
            const float* __restrict__ ba, const float* __restrict__ bb,
            half_t* __restrict__ xall)
{
    __shared__ h8 Gl[64 * 16];

    const int tid  = threadIdx.x;
    const int br   = blockIdx.y;
    const int b    = blockIdx.z;
    const int e0   = blockIdx.x * TILE_E;
    const int lane = tid & 63;
    const int wv   = tid >> 6;
    const int l15  = lane & 15;
    const int kg   = lane >> 4;
    const int eoff = wv * 16;

    const half_t* xb = (br ? x2p : x2e) + (long)b * E_TOT * 128;
    const half_t* wt = war + (br ? OFF_WTB : OFF_WTA);

#pragma unroll
    for (int t = 0; t < 4; ++t) {
        int q = t * 256 + tid;
        int e = q >> 4, c8 = q & 15;
        int eg = e0 + e;
        int se = (eg < E_TOT) ? eg : 0;
        Gl[(e * 16 + c8) ^ (e & 7)] = *(const h8*)(xb + (long)se * 128 + c8 * 8);
    }
    __syncthreads();

    f32x4 acc[2];
#pragma unroll
    for (int nt = 0; nt < 2; ++nt)
#pragma unroll
        for (int j = 0; j < 4; ++j) acc[nt][j] = 0.f;

#pragma unroll
    for (int ks = 0; ks < 4; ++ks) {
        h8 bw[2];
#pragma unroll
        for (int nt = 0; nt < 2; ++nt)
            bw[nt] = *(const h8*)(wt + (long)(nt * 16 + l15) * 128 + ks * 32 + kg * 8);
        int row = eoff + l15;
        h8 a = Gl[row * 16 + ((ks * 4 + kg) ^ (row & 7))];
#pragma unroll
        for (int nt = 0; nt < 2; ++nt)
            acc[nt] = __builtin_amdgcn_mfma_f32_16x16x32_f16(a, bw[nt], acc[nt], 0, 0, 0);
    }

    const float* bias = br ? bb : ba;
    half_t* yb = xall + (long)b * E_TOT * 64;
    int oOff = br * 32;
#pragma unroll
    for (int nt = 0; nt < 2; ++nt) {
        float bv = bias[nt * 16 + l15];
        int ebase = e0 + eoff + (kg << 2);
#pragma unroll
        for (int j = 0; j < 4; ++j) {
            if (ebase + j < E_TOT)
                yb[(long)(ebase + j) * 64 + oOff + nt * 16 + l15] = (half_t)(acc[nt][j] + bv);
        }
    }
}

// ---------------------------------------------------------------------------
// stats finalize, both branch buffers: grid 512 = (br, b, o)
// ---------------------------------------------------------------------------
__global__ __launch_bounds__(256)
void stats2_k(const float* __restrict__ parte, const float* __restrict__ partp,
              float* __restrict__ statse, float* __restrict__ statsp)
{
    int g = blockIdx.x;
    int br = g >> 8, rem = g & 255, b = rem >> 7, o = rem & 127;
    const float* part = br ? partp : parte;
    float* stats = br ? statsp : statse;
    int tid = threadIdx.x;
    float s1 = 0.f, s2 = 0.f;
    for (int k = tid; k < NBLK; k += 256) {
        long base = (((long)b * NBLK + k) * 128 + o) * 2;
        s1 += part[base];
        s2 += part[base + 1];
    }
#pragma unroll
    for (int d = 1; d < 64; d <<= 1) {
        s1 += __shfl_xor(s1, d);
        s2 += __shfl_xor(s2, d);
    }
    __shared__ float r1[4], r2[4];
    int wv = tid >> 6;
    if ((tid & 63) == 0) { r1[wv] = s1; r2[wv] = s2; }
    __syncthreads();
    if (tid == 0) {
        s1 = r1[0] + r1[1] + r1[2] + r1[3];
        s2 = r2[0] + r2[1] + r2[2] + r2[3];
        float mean = s1 / (float)E_TOT;
        float var  = s2 / (float)E_TOT - mean * mean;
        var = fmaxf(var, 0.f);
        stats[(b * 128 + o) * 2 + 0] = mean;
        stats[(b * 128 + o) * 2 + 1] = rsqrtf(var + 1e-5f);
    }
}

// ---------------------------------------------------------------------------
// x1 = relu(inorm(tmp)), both branches in one launch (separate outputs)
// ---------------------------------------------------------------------------
__global__ __launch_bounds__(256)
void norm_act2_k(const half_t* __restrict__ tmpe, const half_t* __restrict__ tmpp,
                 const float* __restrict__ statse, const float* __restrict__ statsp,
                 half_t* __restrict__ x1e, half_t* __restrict__ x1p)
{
    const long PER = (long)B_TOT * E_TOT * 16;   // h8 units per branch
    long q = (long)blockIdx.x * 256 + threadIdx.x;
    if (q >= 2 * PER) return;
    int br = (q >= PER);
    q -= (long)br * PER;
    const half_t* src = br ? tmpp : tmpe;
    const float* stats = br ? statsp : statse;
    half_t* dst = br ? x1p : x1e;
    long idx = q * 8;
    int c = (int)(idx & 127);
    int b = (int)((idx >> 7) / E_TOT);
    h8 v = *(const h8*)&src[idx];
    h8 r;
#pragma unroll
    for (int j = 0; j < 8; ++j) {
        float2 st = *(const float2*)&stats[(b * 128 + c + j) * 2];
        float t = ((float)v[j] - st.x) * st.y;
        r[j] = (half_t)fmaxf(t, 0.f);
    }
    *(h8*)&dst[idx] = r;
}

// ---------------------------------------------------------------------------
// x2 = relu(inorm(tmp)+x1): f32 channel-major out section + f16 copy.
// blockIdx.y = br*4 + cg.
// ---------------------------------------------------------------------------
__global__ __launch_bounds__(256)
void normres2_k(const half_t* __restrict__ tmpe, const half_t* __restrict__ tmpp,
                const half_t* __restrict__ x1e, const half_t* __restrict__ x1p,
                const float* __restrict__ statse, const float* __restrict__ statsp,
                float* __restrict__ outb,
                half_t* __restrict__ x2e, half_t* __restrict__ x2p)
{
    __shared__ float T[32 * 68];
    int br = blockIdx.y >> 2, cg = blockIdx.y & 3;
    int b = blockIdx.z;
    int e0 = blockIdx.x * 64;
    int tid = threadIdx.x;
    const half_t* xin = br ? tmpp : tmpe;
    const half_t* res = br ? x1p : x1e;
    const float* stats = br ? statsp : statse;
    half_t* x2b = br ? x2p : x2e;
    int sect = br * 128;
#pragma unroll
    for (int i = 0; i < 2; ++i) {
        int q = tid + i * 256;
        int e = q >> 3, cq = q & 7;
        int eg = e0 + e;
        int se = (eg < E_TOT) ? eg : (E_TOT - 1);
        int c = cg * 32 + cq * 4;
        long base = ((long)b * E_TOT + se) * 128 + c;
        h4 v4 = *(const h4*)&xin[base];
        h4 r4 = *(const h4*)&res[base];
        h4 o4;
#pragma unroll
        for (int j = 0; j < 4; ++j) {
            float2 st = *(const float2*)&stats[(b * 128 + c + j) * 2];
            float t = ((float)v4[j] - st.x) * st.y + (float)r4[j];
            t = fmaxf(t, 0.f);
            T[(cq * 4 + j) * 68 + e] = t;
            o4[j] = (half_t)t;
        }
        if (eg < E_TOT) *(h4*)&x2b[base] = o4;
    }
    __syncthreads();
#pragma unroll
    for (int i = 0; i < 2; ++i) {
        int q = tid + i * 256;
        int cl = q >> 4, eq = q & 15;
        int e4 = e0 + eq * 4;
        int cglob = sect + cg * 32 + cl;
        float4 v = *(const float4*)&T[cl * 68 + eq * 4];
        long obase = ((long)b * 384 + cglob) * E_TOT + e4;
        if (e4 + 3 < E_TOT) {
            *(float4*)&outb[obase] = v;
        } else {
            const float* vp = &v.x;
            for (int j = 0; j < 4; ++j)
                if (e4 + j < E_TOT) outb[obase + j] = vp[j];
        }
    }
}

// ---------------------------------------------------------------------------
// fused gates-norm + softmax2 + aggregate
// ---------------------------------------------------------------------------
__global__ __launch_bounds__(256)
void gate_agg2_k(const half_t* __restrict__ tA, const half_t* __restrict__ tB,
                 const float* __restrict__ statsA, const float* __restrict__ statsB,
                 const half_t* __restrict__ x2e, const half_t* __restrict__ x2p,
                 float* __restrict__ outb)
{
    __shared__ float T[32 * 68];
    int b = blockIdx.z, cg = blockIdx.y;
    int e0 = blockIdx.x * 64;
    int tid = threadIdx.x;
#pragma unroll
    for (int i = 0; i < 2; ++i) {
        int q = tid + i * 256;
        int e = q >> 3, cq = q & 7;
        int eg = e0 + e;
        int se = (eg < E_TOT) ? eg : (E_TOT - 1);
        int c = cg * 32 + cq * 4;
        long base = ((long)b * E_TOT + se) * 128 + c;
        h4 a4 = *(const h4*)&tA[base];
        h4 b4 = *(const h4*)&tB[base];
        h4 xe4 = *(const h4*)&x2e[base];
        h4 xp4 = *(const h4*)&x2p[base];
#pragma unroll
        for (int j = 0; j < 4; ++j) {
            float2 sa = *(const float2*)&statsA[(b * 128 + c + j) * 2];
            float2 sb = *(const float2*)&statsB[(b * 128 + c + j) * 2];
            float na = sigmoidf_(((float)a4[j] - sa.x) * sa.y);
            float nb = sigmoidf_(((float)b4[j] - sb.x) * sb.y);
            float s = sigmoidf_(na - nb);
            T[(cq * 4 + j) * 68 + e] = (float)xe4[j] * s + (float)xp4[j] * (1.f - s);
        }
    }
    __syncthreads();
#pragma unroll
    for (int i = 0; i < 2; ++i) {
        int q = tid + i * 256;
        int cl = q >> 4, eq = q & 15;
        int e4 = e0 + eq * 4;
        int cglob = cg * 32 + cl;
        float4 v = *(const float4*)&T[cl * 68 + eq * 4];
        long ab = ((long)b * 384 + 256 + cglob) * E_TOT + e4;
        if (e4 + 3 < E_TOT) {
            *(float4*)&outb[ab] = v;
        } else {
            const float* vp = &v.x;
            for (int j = 0; j < 4; ++j)
                if (e4 + j < E_TOT) outb[ab + j] = vp[j];
        }
    }
}

// ---------------------------------------------------------------------------
extern "C" void kernel_launch(void* const* d_in, const int* in_sizes, int n_in,
                              void* d_out, int out_size, void* d_ws, size_t ws_size,
                              hipStream_t stream)
{
    const float* fe   = (const float*)d_in[0];
    const int*   gemm = (const int*)  d_in[1];
    const float* w_e1 = (const float*)d_in[2];  const float* b_e1 = (const float*)d_in[3];
    const float* w_p1 = (const float*)d_in[4];  const float* b_p1 = (const float*)d_in[5];
    const float* w_e2 = (const float*)d_in[6];  const float* b_e2 = (const float*)d_in[7];
    const float* w_p2 = (const float*)d_in[8];  const float* b_p2 = (const float*)d_in[9];
    const float* wa   = (const float*)d_in[10]; const float* ba   = (const float*)d_in[11];
    const float* wb   = (const float*)d_in[12]; const float* bb   = (const float*)d_in[13];
    const float* wal  = (const float*)d_in[14]; const float* bal  = (const float*)d_in[15];
    const float* wbl  = (const float*)d_in[16]; const float* bbl  = (const float*)d_in[17];
    const float* wat  = (const float*)d_in[18]; const float* bat  = (const float*)d_in[19];
    const float* wbt  = (const float*)d_in[20]; const float* bbt  = (const float*)d_in[21];
    const float* waf  = (const float*)d_in[22]; const float* baf  = (const float*)d_in[23];
    const float* wbf  = (const float*)d_in[24]; const float* bbf  = (const float*)d_in[25];
    float* out = (float*)d_out;

    const long EB = (long)E_TOT;

    char* wp = (char*)d_ws;
    auto alloc = [&](size_t bytes) -> void* {
        void* r = (void*)wp;
        wp += (bytes + 255) & ~(size_t)255;
        return r;
    };
    float*  FET    = (float*)alloc((size_t)B_TOT * EB * 8 * 4);
    half_t* TMP_E  = (half_t*)alloc((size_t)B_TOT * EB * 128 * 2);
    half_t* TMP_P  = (half_t*)alloc((size_t)B_TOT * EB * 128 * 2);
    half_t* X1E    = (half_t*)alloc((size_t)B_TOT * EB * 128 * 2);   // later XA2
    half_t* X1P    = (half_t*)alloc((size_t)B_TOT * EB * 128 * 2);   // later XB2
    half_t* X2E    = (half_t*)alloc((size_t)B_TOT * EB * 128 * 2);
    half_t* X2P    = (half_t*)alloc((size_t)B_TOT * EB * 128 * 2);
    half_t* XALL   = (half_t*)alloc((size_t)B_TOT * EB * 64 * 2);
    float*  PART_E = (float*)alloc((size_t)B_TOT * NBLK * 128 * 2 * 4);
    float*  PART_P = (float*)alloc((size_t)B_TOT * NBLK * 128 * 2 * 4);
    float*  STATSE = (float*)alloc((size_t)B_TOT * 128 * 2 * 4);
    float*  STATSP = (float*)alloc((size_t)B_TOT * 128 * 2 * 4);
    half_t* WAR    = (half_t*)alloc((size_t)WARENA_N * 2);

    if ((size_t)(wp - (char*)d_ws) > ws_size) {
        fprintf(stderr, "kernel_launch: ws too small (%zu < %zu)\n",
                ws_size, (size_t)(wp - (char*)d_ws));
        return;
    }

    // X1E/X1P dead after normres2; reuse for decoder-head outputs
    half_t* XA2 = X1E;
    half_t* XB2 = X1P;

    dim3 blk256(256), blk512(512);
    dim3 gI(NBLK, B_TOT);
    dim3 gE2(NBLK, 2, B_TOT);
    dim3 gT((E_TOT + 255) / 256, 1, B_TOT);
    dim3 gN8(NBLK, 8, B_TOT);
    dim3 gN4(NBLK, 4, B_TOT);
    int gA2 = (int)((2 * (long)B_TOT * EB * 16 + 255) / 256);

    // 1-2: prep
    wprep_k<<<dim3(320, 10, 1), blk256, 0, stream>>>(WAR,
        w_e1, w_p1, w_e2, w_p2, wat, wbt, wa, wb, wal, wbl, waf, wbf);
    transpose_in_k<<<gT, blk256, 0, stream>>>(fe, FET);

    // 3-5: layer 1 (both branches)
    mesh1_both_k<<<gI, blk512, 0, stream>>>(FET, gemm, WAR, b_e1, b_p1,
        TMP_E, TMP_P, PART_E, PART_P);
    stats2_k<<<512, blk256, 0, stream>>>(PART_E, PART_P, STATSE, STATSP);
    norm_act2_k<<<gA2, blk256, 0, stream>>>(TMP_E, TMP_P, STATSE, STATSP, X1E, X1P);

    // 6-8: layer 2 (T14-pipelined, one branch per block) + norm/res
    mesh2p_k<<<gE2, blk512, 0, stream>>>(X1E, X1P, gemm, WAR, b_e2, b_p2,
        TMP_E, TMP_P, PART_E, PART_P);
    stats2_k<<<512, blk256, 0, stream>>>(PART_E, PART_P, STATSE, STATSP);
    normres2_k<<<gN8, blk256, 0, stream>>>(TMP_E, TMP_P, X1E, X1P, STATSE, STATSP,
        out, X2E, X2P);

    // 9: x_all
    xall_k<<<gE2, blk256, 0, stream>>>(X2E, X2P, WAR, ba, bb, XALL);

    // 10: decoder heads (A+B merged, shared gather)
    heads2_k<<<gI, blk512, 0, stream>>>(XALL, gemm, WAR, bal, bbl, bat, bbt, XA2, XB2);

    // 11-13: gates + aggregate
    gates_k<<<gE2, blk512, 0, stream>>>(XA2, XB2, WAR, baf, bbf,
        TMP_E, TMP_P, PART_E, PART_P);
    stats2_k<<<512, blk256, 0, stream>>>(PART_E, PART_P, STATSE, STATSP);
    gate_agg2_k<<<gN4, blk256, 0, stream>>>(TMP_E, TMP_P, STATSE, STATSP,
        X2E, X2P, out);
}

// Round 8
// 345.905 us; speedup vs baseline: 1.0862x; 1.0708x over previous
//
#include <hip/hip_runtime.h>
#include <cstdio>
#include <math.h>

// ---------------------------------------------------------------------------
// MeshEncoderDecoder — round 8: mesh2 reverted to R5-measured-best schedule;
// heads+gates fused through LDS (xa2/xb2 eliminated, -102 MB HBM traffic).
// ---------------------------------------------------------------------------

#define E_TOT 50000
#define B_TOT 2
#define TILE_E 64
#define NBLK ((E_TOT + TILE_E - 1) / TILE_E)   // 782

typedef _Float16 half_t;
typedef __attribute__((ext_vector_type(4))) _Float16 h4;
typedef __attribute__((ext_vector_type(8))) _Float16 h8;
typedef __attribute__((ext_vector_type(4))) float f32x4;

__device__ __forceinline__ float sigmoidf_(float x) {
    return 1.0f / (1.0f + __expf(-x));
}
__device__ __forceinline__ h8 habs8(h8 x) {
    union { h8 h; unsigned int u[4]; } v;
    v.h = x;
#pragma unroll
    for (int i = 0; i < 4; ++i) v.u[i] &= 0x7FFF7FFFu;
    return v.h;
}

// ---------------------------------------------------------------------------
// weight arena offsets (halves)
// ---------------------------------------------------------------------------
#define OFF_W1E   0          // 128*64 (k = s*8+cc, zero-padded)
#define OFF_W1P   8192       // 128*64
#define OFF_WTE2  16384      // 128*5*128
#define OFF_WTP2  98304      // 128*5*128
#define OFF_WHA   180224     // 128*5*64 (o<64: wal in s0; o>=64: wat)
#define OFF_WHB   221184     // 128*5*64
#define OFF_WTA   262144     // 32*128
#define OFF_WTB   266240     // 32*128
#define OFF_WTAF  270336     // 128*128
#define OFF_WTBF  286720     // 128*128
#define WARENA_N  303104

__global__ __launch_bounds__(256)
void wprep_k(half_t* __restrict__ wa_,
             const float* __restrict__ w_e1, const float* __restrict__ w_p1,
             const float* __restrict__ w_e2, const float* __restrict__ w_p2,
             const float* __restrict__ wat,  const float* __restrict__ wbt,
             const float* __restrict__ wa,   const float* __restrict__ wb,
             const float* __restrict__ wal,  const float* __restrict__ wbl,
             const float* __restrict__ waf,  const float* __restrict__ wbf)
{
    int idx = blockIdx.x * 256 + threadIdx.x;
    switch (blockIdx.y) {
    case 0: if (idx < 8192) { int o = idx >> 6, k = idx & 63, s = k >> 3, cc = k & 7;
            float v = (s < 5 && cc < 5) ? w_e1[o * 25 + cc * 5 + s] : 0.f;
            wa_[OFF_W1E + idx] = (half_t)v; } break;
    case 1: if (idx < 8192) { int o = idx >> 6, k = idx & 63, s = k >> 3, cc = k & 7;
            float v = (s < 5 && cc >= 5) ? w_p1[o * 15 + (cc - 5) * 5 + s] : 0.f;
            wa_[OFF_W1P + idx] = (half_t)v; } break;
    case 2: if (idx < 81920) { int o = idx / 640, r = idx % 640, s = r >> 7, c = r & 127;
            wa_[OFF_WTE2 + idx] = (half_t)w_e2[(o * 128 + c) * 5 + s]; } break;
    case 3: if (idx < 81920) { int o = idx / 640, r = idx % 640, s = r >> 7, c = r & 127;
            wa_[OFF_WTP2 + idx] = (half_t)w_p2[(o * 128 + c) * 5 + s]; } break;
    case 4: if (idx < 40960) { int o = idx / 320, r = idx % 320, s = r >> 6, c = r & 63;
            float v = (o < 64) ? (s == 0 ? wal[o * 64 + c] : 0.f)
                               : wat[((o - 64) * 64 + c) * 5 + s];
            wa_[OFF_WHA + idx] = (half_t)v; } break;
    case 5: if (idx < 40960) { int o = idx / 320, r = idx % 320, s = r >> 6, c = r & 63;
            float v = (o < 64) ? (s == 0 ? wbl[o * 64 + c] : 0.f)
                               : wbt[((o - 64) * 64 + c) * 5 + s];
            wa_[OFF_WHB + idx] = (half_t)v; } break;
    case 6: if (idx < 4096)  wa_[OFF_WTA  + idx] = (half_t)wa[idx];  break;
    case 7: if (idx < 4096)  wa_[OFF_WTB  + idx] = (half_t)wb[idx];  break;
    case 8: if (idx < 16384) wa_[OFF_WTAF + idx] = (half_t)waf[idx]; break;
    case 9: if (idx < 16384) wa_[OFF_WTBF + idx] = (half_t)wbf[idx]; break;
    }
}

// ---------------------------------------------------------------------------
// transpose fe (b, 8, E) -> fe_t (b, E, 8) f32
// ---------------------------------------------------------------------------
__global__ __launch_bounds__(256)
void transpose_in_k(const float* __restrict__ fe, float* __restrict__ fet)
{
    int b = blockIdx.z;
    int e = blockIdx.x * 256 + threadIdx.x;
    if (e >= E_TOT) return;
    float v[8];
#pragma unroll
    for (int c = 0; c < 8; ++c)
        v[c] = fe[((long)b * 8 + c) * E_TOT + e];
    float4* dst = (float4*)&fet[((long)b * E_TOT + e) * 8];
    dst[0] = make_float4(v[0], v[1], v[2], v[3]);
    dst[1] = make_float4(v[4], v[5], v[6], v[7]);
}

// ---------------------------------------------------------------------------
// layer-1 both branches: shared G, K=64, 8 waves (0-3 edge, 4-7 point)
// ---------------------------------------------------------------------------
__global__ __launch_bounds__(512)
void mesh1_both_k(const float* __restrict__ fet, const int* __restrict__ gemm,
                  const half_t* __restrict__ war,
                  const float* __restrict__ be1, const float* __restrict__ bp1,
                  half_t* __restrict__ tmpe, half_t* __restrict__ tmpp,
                  float* __restrict__ parte, float* __restrict__ partp)
{
    __shared__ h8 Gl[64 * 8];
    __shared__ int nidx[64][4];

    const int tid  = threadIdx.x;
    const int b    = blockIdx.y;
    const int e0   = blockIdx.x * TILE_E;
    const int lane = tid & 63;
    const int wv   = tid >> 6;
    const int l15  = lane & 15;
    const int kg   = lane >> 4;
    const int br   = wv >> 2;
    const int o0   = (wv & 3) * 32;

    const float* xb = fet + (long)b * E_TOT * 8;

    if (tid < 256) {
        int e = tid >> 2, s = tid & 3;
        int eg = e0 + e;
        nidx[e][s] = (eg < E_TOT) ? gemm[((long)b * E_TOT + eg) * 4 + s] : 0;
    }
    __syncthreads();

    {
        int e = tid >> 3, g = tid & 7;
        int eg = e0 + e;
        int se = (eg < E_TOT) ? eg : 0;
        h8 r;
        if (g == 0) {
            const float* p = xb + (long)se * 8;
            float4 v0 = *(const float4*)p, v1 = *(const float4*)(p + 4);
            r[0] = (half_t)v0.x; r[1] = (half_t)v0.y; r[2] = (half_t)v0.z; r[3] = (half_t)v0.w;
            r[4] = (half_t)v1.x; r[5] = (half_t)v1.y; r[6] = (half_t)v1.z; r[7] = (half_t)v1.w;
        } else if (g <= 4) {
            int ia = (g == 1 || g == 3) ? 0 : 1;
            const float* pa = xb + (long)nidx[e][ia] * 8;
            const float* pb = xb + (long)nidx[e][ia + 2] * 8;
            float4 a0 = *(const float4*)pa, a1 = *(const float4*)(pa + 4);
            float4 b0 = *(const float4*)pb, b1 = *(const float4*)(pb + 4);
            float aa[8] = {a0.x, a0.y, a0.z, a0.w, a1.x, a1.y, a1.z, a1.w};
            float bb[8] = {b0.x, b0.y, b0.z, b0.w, b1.x, b1.y, b1.z, b1.w};
            if (g <= 2) {
#pragma unroll
                for (int j = 0; j < 8; ++j) r[j] = (half_t)(aa[j] + bb[j]);
            } else {
#pragma unroll
                for (int j = 0; j < 8; ++j) r[j] = (half_t)fabsf(aa[j] - bb[j]);
            }
        } else {
#pragma unroll
            for (int j = 0; j < 8; ++j) r[j] = (half_t)0.f;
        }
        Gl[(e * 8 + g) ^ (e & 7)] = r;
    }
    __syncthreads();

    f32x4 acc[4][2];
#pragma unroll
    for (int mt = 0; mt < 4; ++mt)
#pragma unroll
        for (int nt = 0; nt < 2; ++nt)
#pragma unroll
            for (int j = 0; j < 4; ++j) acc[mt][nt][j] = 0.f;

    const half_t* wt = war + (br ? OFF_W1P : OFF_W1E);
#pragma unroll
    for (int ks = 0; ks < 2; ++ks) {
        h8 bw[2];
#pragma unroll
        for (int nt = 0; nt < 2; ++nt)
            bw[nt] = *(const h8*)(wt + (long)(o0 + nt * 16 + l15) * 64 + ks * 32 + kg * 8);
#pragma unroll
        for (int mt = 0; mt < 4; ++mt) {
            int row = mt * 16 + l15;
            h8 a = Gl[row * 8 + ((ks * 4 + kg) ^ (row & 7))];
#pragma unroll
            for (int nt = 0; nt < 2; ++nt)
                acc[mt][nt] = __builtin_amdgcn_mfma_f32_16x16x32_f16(a, bw[nt], acc[mt][nt], 0, 0, 0);
        }
    }

    const float* bias = br ? bp1 : be1;
    half_t* yb = (br ? tmpp : tmpe) + (long)b * E_TOT * 128;
    float* part = br ? partp : parte;
    float bv[2], s1[2], s2[2];
#pragma unroll
    for (int nt = 0; nt < 2; ++nt) {
        bv[nt] = bias[o0 + nt * 16 + l15];
        s1[nt] = 0.f; s2[nt] = 0.f;
    }
#pragma unroll
    for (int mt = 0; mt < 4; ++mt) {
        int ebase = e0 + mt * 16 + (kg << 2);
#pragma unroll
        for (int j = 0; j < 4; ++j) {
            if (ebase + j < E_TOT) {
#pragma unroll
                for (int nt = 0; nt < 2; ++nt) {
                    float v = acc[mt][nt][j] + bv[nt];
                    yb[(long)(ebase + j) * 128 + o0 + nt * 16 + l15] = (half_t)v;
                    s1[nt] += v; s2[nt] += v * v;
                }
            }
        }
    }
#pragma unroll
    for (int nt = 0; nt < 2; ++nt) {
        s1[nt] += __shfl_xor(s1[nt], 16); s1[nt] += __shfl_xor(s1[nt], 32);
        s2[nt] += __shfl_xor(s2[nt], 16); s2[nt] += __shfl_xor(s2[nt], 32);
    }
    if (lane < 16) {
        long pb = ((long)b * NBLK + blockIdx.x) * 128;
#pragma unroll
        for (int nt = 0; nt < 2; ++nt) {
            part[(pb + o0 + nt * 16 + lane) * 2 + 0] = s1[nt];
            part[(pb + o0 + nt * 16 + lane) * 2 + 1] = s2[nt];
        }
    }
}

// ---------------------------------------------------------------------------
// layer-2 mesh conv — R5-measured-best schedule (stage, sync, compute; no
// register prefetch). One branch per block (blockIdx.y), 8 waves, 33 KB LDS.
// ---------------------------------------------------------------------------
__global__ __launch_bounds__(512)
void mesh2_k(const half_t* __restrict__ x1e, const half_t* __restrict__ x1p,
             const int* __restrict__ gemm, const half_t* __restrict__ war,
             const float* __restrict__ be, const float* __restrict__ bp,
             half_t* __restrict__ tmpe, half_t* __restrict__ tmpp,
             float* __restrict__ parte, float* __restrict__ partp)
{
    __shared__ h8 GlA[64 * 16];
    __shared__ h8 GlB[64 * 16];
    __shared__ int nidx[64][4];

    const int tid  = threadIdx.x;
    const int br   = blockIdx.y;
    const int b    = blockIdx.z;
    const int e0   = blockIdx.x * TILE_E;
    const int lane = tid & 63;
    const int wv   = tid >> 6;
    const int l15  = lane & 15;
    const int kg   = lane >> 4;
    const int o0   = wv * 16;

    const half_t* xb = (br ? x1p : x1e) + (long)b * E_TOT * 128;
    const half_t* wt = war + (br ? OFF_WTP2 : OFF_WTE2);

    if (tid < 256) {
        int e = tid >> 2, s = tid & 3;
        int eg = e0 + e;
        nidx[e][s] = (eg < E_TOT) ? gemm[((long)b * E_TOT + eg) * 4 + s] : 0;
    }

    auto stage_self = [&](h8* dst) {
#pragma unroll
        for (int t = 0; t < 2; ++t) {
            int q = t * 512 + tid;
            int e = q >> 4, c8 = q & 15;
            int eg = e0 + e;
            int se = (eg < E_TOT) ? eg : 0;
            dst[(e * 16 + c8) ^ (e & 7)] = *(const h8*)(xb + (long)se * 128 + c8 * 8);
        }
    };
    auto stage_pair = [&](h8* dstS, h8* dstD, int ia, int ib) {
#pragma unroll
        for (int t = 0; t < 2; ++t) {
            int q = t * 512 + tid;
            int e = q >> 4, c8 = q & 15;
            int na = nidx[e][ia], nb = nidx[e][ib];
            h8 a  = *(const h8*)(xb + (long)na * 128 + c8 * 8);
            h8 bq = *(const h8*)(xb + (long)nb * 128 + c8 * 8);
            int slot = (e * 16 + c8) ^ (e & 7);
            dstS[slot] = a + bq;
            dstD[slot] = habs8(a - bq);
        }
    };

    f32x4 acc[4];
#pragma unroll
    for (int mt = 0; mt < 4; ++mt)
#pragma unroll
        for (int j = 0; j < 4; ++j) acc[mt][j] = 0.f;

    auto compute_chunk = [&](const h8* buf, int s) {
#pragma unroll
        for (int ks = 0; ks < 4; ++ks) {
            h8 bw = *(const h8*)(wt + ((long)(o0 + l15) * 5 + s) * 128 + ks * 32 + kg * 8);
#pragma unroll
            for (int mt = 0; mt < 4; ++mt) {
                int row = mt * 16 + l15;
                h8 a = buf[row * 16 + ((ks * 4 + kg) ^ (row & 7))];
                acc[mt] = __builtin_amdgcn_mfma_f32_16x16x32_f16(a, bw, acc[mt], 0, 0, 0);
            }
        }
    };

    stage_self(GlA);
    __syncthreads();
    compute_chunk(GlA, 0);
    __syncthreads();
    stage_pair(GlA, GlB, 0, 2);
    __syncthreads();
    compute_chunk(GlA, 1);
    compute_chunk(GlB, 3);
    __syncthreads();
    stage_pair(GlA, GlB, 1, 3);
    __syncthreads();
    compute_chunk(GlA, 2);
    compute_chunk(GlB, 4);

    const float* bias = br ? bp : be;
    half_t* yb = (br ? tmpp : tmpe) + (long)b * E_TOT * 128;
    float* part = br ? partp : parte;
    float bv = bias[o0 + l15];
    float s1 = 0.f, s2 = 0.f;
#pragma unroll
    for (int mt = 0; mt < 4; ++mt) {
        int ebase = e0 + mt * 16 + (kg << 2);
#pragma unroll
        for (int j = 0; j < 4; ++j) {
            if (ebase + j < E_TOT) {
                float v = acc[mt][j] + bv;
                yb[(long)(ebase + j) * 128 + o0 + l15] = (half_t)v;
                s1 += v; s2 += v * v;
            }
        }
    }
    s1 += __shfl_xor(s1, 16); s1 += __shfl_xor(s1, 32);
    s2 += __shfl_xor(s2, 16); s2 += __shfl_xor(s2, 32);
    if (lane < 16) {
        long pb = ((long)b * NBLK + blockIdx.x) * 128;
        part[(pb + o0 + lane) * 2 + 0] = s1;
        part[(pb + o0 + lane) * 2 + 1] = s2;
    }
}

// ---------------------------------------------------------------------------
// FUSED decoder heads + gates. Heads (A+B, linear+mesh) computed from shared
// xall gather; outputs land in a 32 KB LDS arena (aliased over the gather
// buffers); gate GEMM reads the tile in-block. xa2/xb2 never touch HBM.
// waves: hd = wv>>2 (0=A/gateA, 1=B/gateB), o-quadrant = wv&3.
// ---------------------------------------------------------------------------
__global__ __launch_bounds__(512)
void heads_gates_k(const half_t* __restrict__ xall, const int* __restrict__ gemm,
                   const half_t* __restrict__ war,
                   const float* __restrict__ bal, const float* __restrict__ bbl,
                   const float* __restrict__ bat, const float* __restrict__ bbt,
                   const float* __restrict__ baf, const float* __restrict__ bbf,
                   half_t* __restrict__ tmpe, half_t* __restrict__ tmpp,
                   float* __restrict__ parte, float* __restrict__ partp)
{
    __shared__ h8 arena[2048];     // 32 KB: phase H = C0|C1|C2 (24 KB); phase G = XA|XB
    __shared__ int nidx[64][4];

    const int tid  = threadIdx.x;
    const int b    = blockIdx.y;
    const int e0   = blockIdx.x * TILE_E;
    const int lane = tid & 63;
    const int wv   = tid >> 6;
    const int hd   = wv >> 2;
    const int o0   = (wv & 3) * 32;
    const int l15  = lane & 15;
    const int kg   = lane >> 4;

    h8* C0 = arena;
    h8* C1 = arena + 512;
    h8* C2 = arena + 1024;

    const half_t* xb = xall + (long)b * E_TOT * 64;

    if (tid < 256) {
        int e = tid >> 2, s = tid & 3;
        int eg = e0 + e;
        nidx[e][s] = (eg < E_TOT) ? gemm[((long)b * E_TOT + eg) * 4 + s] : 0;
    }
    __syncthreads();

    const int te = tid >> 3, tc = tid & 7;
    const int tslot = (te * 8 + tc) ^ (te & 7);

    {
        int eg = e0 + te;
        int se = (eg < E_TOT) ? eg : 0;
        C0[tslot] = *(const h8*)(xb + (long)se * 64 + tc * 8);
    }
    h8 rA, rB;
    {
        rA = *(const h8*)(xb + (long)nidx[te][0] * 64 + tc * 8);
        rB = *(const h8*)(xb + (long)nidx[te][2] * 64 + tc * 8);
    }
    __syncthreads();

    f32x4 acc[4][2];
#pragma unroll
    for (int mt = 0; mt < 4; ++mt)
#pragma unroll
        for (int nt = 0; nt < 2; ++nt)
#pragma unroll
            for (int j = 0; j < 4; ++j) acc[mt][nt][j] = 0.f;

    const half_t* wt = war + (hd ? OFF_WHB : OFF_WHA);
    auto chunk = [&](const h8* buf, int s) {
#pragma unroll
        for (int ks = 0; ks < 2; ++ks) {
            h8 bw0 = *(const h8*)(wt + ((long)(o0 + l15) * 5 + s) * 64 + ks * 32 + kg * 8);
            h8 bw1 = *(const h8*)(wt + ((long)(o0 + 16 + l15) * 5 + s) * 64 + ks * 32 + kg * 8);
#pragma unroll
            for (int mt = 0; mt < 4; ++mt) {
                int row = mt * 16 + l15;
                h8 a = buf[row * 8 + ((ks * 4 + kg) ^ (row & 7))];
                acc[mt][0] = __builtin_amdgcn_mfma_f32_16x16x32_f16(a, bw0, acc[mt][0], 0, 0, 0);
                acc[mt][1] = __builtin_amdgcn_mfma_f32_16x16x32_f16(a, bw1, acc[mt][1], 0, 0, 0);
            }
        }
    };

    chunk(C0, 0);
    __syncthreads();
    {
        C1[tslot] = rA + rB;
        C2[tslot] = habs8(rA - rB);
        rA = *(const h8*)(xb + (long)nidx[te][1] * 64 + tc * 8);
        rB = *(const h8*)(xb + (long)nidx[te][3] * 64 + tc * 8);
    }
    __syncthreads();
    chunk(C1, 1);
    chunk(C2, 3);
    __syncthreads();
    {
        C1[tslot] = rA + rB;
        C2[tslot] = habs8(rA - rB);
    }
    __syncthreads();
    chunk(C1, 2);
    chunk(C2, 4);
    __syncthreads();               // all reads of C done — arena reusable

    // ---- write head outputs (+bias) into X tiles, swizzled [e][c] layout
    {
        half_t* X = (half_t*)(arena + hd * 1024);
        float bv[2];
#pragma unroll
        for (int nt = 0; nt < 2; ++nt) {
            int o = o0 + nt * 16 + l15;
            bv[nt] = (o < 64) ? (hd ? bbl[o] : bal[o]) : (hd ? bbt[o - 64] : bat[o - 64]);
        }
#pragma unroll
        for (int mt = 0; mt < 4; ++mt) {
#pragma unroll
            for (int j = 0; j < 4; ++j) {
                int e = mt * 16 + (kg << 2) + j;
#pragma unroll
                for (int nt = 0; nt < 2; ++nt) {
                    int c = o0 + nt * 16 + l15;
                    int slot = (e * 16 + (c >> 3)) ^ (e & 7);
                    X[slot * 8 + (c & 7)] = (half_t)(acc[mt][nt][j] + bv[nt]);
                }
            }
        }
    }
    __syncthreads();

    // ---- gate GEMM from LDS tile: wave (hd,q) -> gate-hd outs o0..o0+31
    f32x4 g[4][2];
#pragma unroll
    for (int mt = 0; mt < 4; ++mt)
#pragma unroll
        for (int nt = 0; nt < 2; ++nt)
#pragma unroll
            for (int j = 0; j < 4; ++j) g[mt][nt][j] = 0.f;

    const half_t* wtg = war + (hd ? OFF_WTBF : OFF_WTAF);
    const h8* X = arena + hd * 1024;
#pragma unroll
    for (int ks = 0; ks < 4; ++ks) {
        h8 bw0 = *(const h8*)(wtg + (long)(o0 + l15) * 128 + ks * 32 + kg * 8);
        h8 bw1 = *(const h8*)(wtg + (long)(o0 + 16 + l15) * 128 + ks * 32 + kg * 8);
#pragma unroll
        for (int mt = 0; mt < 4; ++mt) {
            int row = mt * 16 + l15;
            h8 a = X[row * 16 + ((ks * 4 + kg) ^ (row & 7))];
            g[mt][0] = __builtin_amdgcn_mfma_f32_16x16x32_f16(a, bw0, g[mt][0], 0, 0, 0);
            g[mt][1] = __builtin_amdgcn_mfma_f32_16x16x32_f16(a, bw1, g[mt][1], 0, 0, 0);
        }
    }

    const float* biasg = hd ? bbf : baf;
    half_t* yb = (hd ? tmpp : tmpe) + (long)b * E_TOT * 128;
    float* part = hd ? partp : parte;
    float bg[2] = {biasg[o0 + l15], biasg[o0 + 16 + l15]};
    float s1[2] = {0.f, 0.f}, s2[2] = {0.f, 0.f};
#pragma unroll
    for (int mt = 0; mt < 4; ++mt) {
        int ebase = e0 + mt * 16 + (kg << 2);
#pragma unroll
        for (int j = 0; j < 4; ++j) {
            if (ebase + j < E_TOT) {
#pragma unroll
                for (int nt = 0; nt < 2; ++nt) {
                    float v = g[mt][nt][j] + bg[nt];
                    yb[(long)(ebase + j) * 128 + o0 + nt * 16 + l15] = (half_t)v;
                    s1[nt] += v; s2[nt] += v * v;
                }
            }
        }
    }
#pragma unroll
    for (int nt = 0; nt < 2; ++nt) {
        s1[nt] += __shfl_xor(s1[nt], 16); s1[nt] += __shfl_xor(s1[nt], 32);
        s2[nt] += __shfl_xor(s2[nt], 16); s2[nt] += __shfl_xor(s2[nt], 32);
    }
    if (lane < 16) {
        long pb = ((long)b * NBLK + blockIdx.x) * 128;
#pragma unroll
        for (int nt = 0; nt < 2; ++nt) {
            part[(pb + o0 + nt * 16 + lane) * 2 + 0] = s1[nt];
            part[(pb + o0 + nt * 16 + lane) * 2 + 1] = s2[nt];
        }
    }
}

// ---------------------------------------------------------------------------
// x_all: 1x1 conv C=128 -> O=32, both halves via blockIdx.y
// ---------------------------------------------------------------------------
__global__ __launch_bounds__(256)
void xall_k(const half_t* __restrict__ x2e, const half_t* __restrict__ x2p,
            const half_t* __restrict__ war,
            const float* __restrict__ ba, const float* __restrict__ bb,
            half_t* __restrict__ xall)
{
    __shared__ h8 Gl[64 * 16];

    const int tid  = threadIdx.x;
    const int br   = blockIdx.y;
    const int b    = blockIdx.z;
    const int e0   = blockIdx.x * TILE_E;
    const int lane = tid & 63;
    const int wv   = tid >> 6;
    const int l15  = lane & 15;
    const int kg   = lane >> 4;
    const int eoff = wv * 16;

    const half_t* xb = (br ? x2p : x2e) + (long)b * E_TOT * 128;
    const half_t* wt = war + (br ? OFF_WTB : OFF_WTA);

#pragma unroll
    for (int t = 0; t < 4; ++t) {
        int q = t * 256 + tid;
        int e = q >> 4, c8 = q & 15;
        int eg = e0 + e;
        int se = (eg < E_TOT) ? eg : 0;
        Gl[(e * 16 + c8) ^ (e & 7)] = *(const h8*)(xb + (long)se * 128 + c8 * 8);
    }
    __syncthreads();

    f32x4 acc[2];
#pragma unroll
    for (int nt = 0; nt < 2; ++nt)
#pragma unroll
        for (int j = 0; j < 4; ++j) acc[nt][j] = 0.f;

#pragma unroll
    for (int ks = 0; ks < 4; ++ks) {
        h8 bw[2];
#pragma unroll
        for (int nt = 0; nt < 2; ++nt)
            bw[nt] = *(const h8*)(wt + (long)(nt * 16 + l15) * 128 + ks * 32 + kg * 8);
        int row = eoff + l15;
        h8 a = Gl[row * 16 + ((ks * 4 + kg) ^ (row & 7))];
#pragma unroll
        for (int nt = 0; nt < 2; ++nt)
            acc[nt] = __builtin_amdgcn_mfma_f32_16x16x32_f16(a, bw[nt], acc[nt], 0, 0, 0);
    }

    const float* bias = br ? bb : ba;
    half_t* yb = xall + (long)b * E_TOT * 64;
    int oOff = br * 32;
#pragma unroll
    for (int nt = 0; nt < 2; ++nt) {
        float bv = bias[nt * 16 + l15];
        int ebase = e0 + eoff + (kg << 2);
#pragma unroll
        for (int j = 0; j < 4; ++j) {
            if (ebase + j < E_TOT)
                yb[(long)(ebase + j) * 64 + oOff + nt * 16 + l15] = (half_t)(acc[nt][j] + bv);
        }
    }
}

// ---------------------------------------------------------------------------
// stats finalize, both branch buffers: grid 512 = (br, b, o)
// ---------------------------------------------------------------------------
__global__ __launch_bounds__(256)
void stats2_k(const float* __restrict__ parte, const float* __restrict__ partp,
              float* __restrict__ statse, float* __restrict__ statsp)
{
    int g = blockIdx.x;
    int br = g >> 8, rem = g & 255, b = rem >> 7, o = rem & 127;
    const float* part = br ? partp : parte;
    float* stats = br ? statsp : statse;
    int tid = threadIdx.x;
    float s1 = 0.f, s2 = 0.f;
    for (int k = tid; k < NBLK; k += 256) {
        long base = (((long)b * NBLK + k) * 128 + o) * 2;
        s1 += part[base];
        s2 += part[base + 1];
    }
#pragma unroll
    for (int d = 1; d < 64; d <<= 1) {
        s1 += __shfl_xor(s1, d);
        s2 += __shfl_xor(s2, d);
    }
    __shared__ float r1[4], r2[4];
    int wv = tid >> 6;
    if ((tid & 63) == 0) { r1[wv] = s1; r2[wv] = s2; }
    __syncthreads();
    if (tid == 0) {
        s1 = r1[0] + r1[1] + r1[2] + r1[3];
        s2 = r2[0] + r2[1] + r2[2] + r2[3];
        float mean = s1 / (float)E_TOT;
        float var  = s2 / (float)E_TOT - mean * mean;
        var = fmaxf(var, 0.f);
        stats[(b * 128 + o) * 2 + 0] = mean;
        stats[(b * 128 + o) * 2 + 1] = rsqrtf(var + 1e-5f);
    }
}

// ---------------------------------------------------------------------------
// x1 = relu(inorm(tmp)), both branches in one launch
// ---------------------------------------------------------------------------
__global__ __launch_bounds__(256)
void norm_act2_k(const half_t* __restrict__ tmpe, const half_t* __restrict__ tmpp,
                 const float* __restrict__ statse, const float* __restrict__ statsp,
                 half_t* __restrict__ x1e, half_t* __restrict__ x1p)
{
    const long PER = (long)B_TOT * E_TOT * 16;
    long q = (long)blockIdx.x * 256 + threadIdx.x;
    if (q >= 2 * PER) return;
    int br = (q >= PER);
    q -= (long)br * PER;
    const half_t* src = br ? tmpp : tmpe;
    const float* stats = br ? statsp : statse;
    half_t* dst = br ? x1p : x1e;
    long idx = q * 8;
    int c = (int)(idx & 127);
    int b = (int)((idx >> 7) / E_TOT);
    h8 v = *(const h8*)&src[idx];
    h8 r;
#pragma unroll
    for (int j = 0; j < 8; ++j) {
        float2 st = *(const float2*)&stats[(b * 128 + c + j) * 2];
        float t = ((float)v[j] - st.x) * st.y;
        r[j] = (half_t)fmaxf(t, 0.f);
    }
    *(h8*)&dst[idx] = r;
}

// ---------------------------------------------------------------------------
// x2 = relu(inorm(tmp)+x1): f32 channel-major out section + f16 copy
// ---------------------------------------------------------------------------
__global__ __launch_bounds__(256)
void normres2_k(const half_t* __restrict__ tmpe, const half_t* __restrict__ tmpp,
                const half_t* __restrict__ x1e, const half_t* __restrict__ x1p,
                const float* __restrict__ statse, const float* __restrict__ statsp,
                float* __restrict__ outb,
                half_t* __restrict__ x2e, half_t* __restrict__ x2p)
{
    __shared__ float T[32 * 68];
    int br = blockIdx.y >> 2, cg = blockIdx.y & 3;
    int b = blockIdx.z;
    int e0 = blockIdx.x * 64;
    int tid = threadIdx.x;
    const half_t* xin = br ? tmpp : tmpe;
    const half_t* res = br ? x1p : x1e;
    const float* stats = br ? statsp : statse;
    half_t* x2b = br ? x2p : x2e;
    int sect = br * 128;
#pragma unroll
    for (int i = 0; i < 2; ++i) {
        int q = tid + i * 256;
        int e = q >> 3, cq = q & 7;
        int eg = e0 + e;
        int se = (eg < E_TOT) ? eg : (E_TOT - 1);
        int c = cg * 32 + cq * 4;
        long base = ((long)b * E_TOT + se) * 128 + c;
        h4 v4 = *(const h4*)&xin[base];
        h4 r4 = *(const h4*)&res[base];
        h4 o4;
#pragma unroll
        for (int j = 0; j < 4; ++j) {
            float2 st = *(const float2*)&stats[(b * 128 + c + j) * 2];
            float t = ((float)v4[j] - st.x) * st.y + (float)r4[j];
            t = fmaxf(t, 0.f);
            T[(cq * 4 + j) * 68 + e] = t;
            o4[j] = (half_t)t;
        }
        if (eg < E_TOT) *(h4*)&x2b[base] = o4;
    }
    __syncthreads();
#pragma unroll
    for (int i = 0; i < 2; ++i) {
        int q = tid + i * 256;
        int cl = q >> 4, eq = q & 15;
        int e4 = e0 + eq * 4;
        int cglob = sect + cg * 32 + cl;
        float4 v = *(const float4*)&T[cl * 68 + eq * 4];
        long obase = ((long)b * 384 + cglob) * E_TOT + e4;
        if (e4 + 3 < E_TOT) {
            *(float4*)&outb[obase] = v;
        } else {
            const float* vp = &v.x;
            for (int j = 0; j < 4; ++j)
                if (e4 + j < E_TOT) outb[obase + j] = vp[j];
        }
    }
}

// ---------------------------------------------------------------------------
// fused gates-norm + softmax2 + aggregate
// ---------------------------------------------------------------------------
__global__ __launch_bounds__(256)
void gate_agg2_k(const half_t* __restrict__ tA, const half_t* __restrict__ tB,
                 const float* __restrict__ statsA, const float* __restrict__ statsB,
                 const half_t* __restrict__ x2e, const half_t* __restrict__ x2p,
                 float* __restrict__ outb)
{
    __shared__ float T[32 * 68];
    int b = blockIdx.z, cg = blockIdx.y;
    int e0 = blockIdx.x * 64;
    int tid = threadIdx.x;
#pragma unroll
    for (int i = 0; i < 2; ++i) {
        int q = tid + i * 256;
        int e = q >> 3, cq = q & 7;
        int eg = e0 + e;
        int se = (eg < E_TOT) ? eg : (E_TOT - 1);
        int c = cg * 32 + cq * 4;
        long base = ((long)b * E_TOT + se) * 128 + c;
        h4 a4 = *(const h4*)&tA[base];
        h4 b4 = *(const h4*)&tB[base];
        h4 xe4 = *(const h4*)&x2e[base];
        h4 xp4 = *(const h4*)&x2p[base];
#pragma unroll
        for (int j = 0; j < 4; ++j) {
            float2 sa = *(const float2*)&statsA[(b * 128 + c + j) * 2];
            float2 sb = *(const float2*)&statsB[(b * 128 + c + j) * 2];
            float na = sigmoidf_(((float)a4[j] - sa.x) * sa.y);
            float nb = sigmoidf_(((float)b4[j] - sb.x) * sb.y);
            float s = sigmoidf_(na - nb);
            T[(cq * 4 + j) * 68 + e] = (float)xe4[j] * s + (float)xp4[j] * (1.f - s);
        }
    }
    __syncthreads();
#pragma unroll
    for (int i = 0; i < 2; ++i) {
        int q = tid + i * 256;
        int cl = q >> 4, eq = q & 15;
        int e4 = e0 + eq * 4;
        int cglob = cg * 32 + cl;
        float4 v = *(const float4*)&T[cl * 68 + eq * 4];
        long ab = ((long)b * 384 + 256 + cglob) * E_TOT + e4;
        if (e4 + 3 < E_TOT) {
            *(float4*)&outb[ab] = v;
        } else {
            const float* vp = &v.x;
            for (int j = 0; j < 4; ++j)
                if (e4 + j < E_TOT) outb[ab + j] = vp[j];
        }
    }
}

// ---------------------------------------------------------------------------
extern "C" void kernel_launch(void* const* d_in, const int* in_sizes, int n_in,
                              void* d_out, int out_size, void* d_ws, size_t ws_size,
                              hipStream_t stream)
{
    const float* fe   = (const float*)d_in[0];
    const int*   gemm = (const int*)  d_in[1];
    const float* w_e1 = (const float*)d_in[2];  const float* b_e1 = (const float*)d_in[3];
    const float* w_p1 = (const float*)d_in[4];  const float* b_p1 = (const float*)d_in[5];
    const float* w_e2 = (const float*)d_in[6];  const float* b_e2 = (const float*)d_in[7];
    const float* w_p2 = (const float*)d_in[8];  const float* b_p2 = (const float*)d_in[9];
    const float* wa   = (const float*)d_in[10]; const float* ba   = (const float*)d_in[11];
    const float* wb   = (const float*)d_in[12]; const float* bb   = (const float*)d_in[13];
    const float* wal  = (const float*)d_in[14]; const float* bal  = (const float*)d_in[15];
    const float* wbl  = (const float*)d_in[16]; const float* bbl  = (const float*)d_in[17];
    const float* wat  = (const float*)d_in[18]; const float* bat  = (const float*)d_in[19];
    const float* wbt  = (const float*)d_in[20]; const float* bbt  = (const float*)d_in[21];
    const float* waf  = (const float*)d_in[22]; const float* baf  = (const float*)d_in[23];
    const float* wbf  = (const float*)d_in[24]; const float* bbf  = (const float*)d_in[25];
    float* out = (float*)d_out;

    const long EB = (long)E_TOT;

    char* wp = (char*)d_ws;
    auto alloc = [&](size_t bytes) -> void* {
        void* r = (void*)wp;
        wp += (bytes + 255) & ~(size_t)255;
        return r;
    };
    float*  FET    = (float*)alloc((size_t)B_TOT * EB * 8 * 4);
    half_t* TMP_E  = (half_t*)alloc((size_t)B_TOT * EB * 128 * 2);
    half_t* TMP_P  = (half_t*)alloc((size_t)B_TOT * EB * 128 * 2);
    half_t* X1E    = (half_t*)alloc((size_t)B_TOT * EB * 128 * 2);
    half_t* X1P    = (half_t*)alloc((size_t)B_TOT * EB * 128 * 2);
    half_t* X2E    = (half_t*)alloc((size_t)B_TOT * EB * 128 * 2);
    half_t* X2P    = (half_t*)alloc((size_t)B_TOT * EB * 128 * 2);
    half_t* XALL   = (half_t*)alloc((size_t)B_TOT * EB * 64 * 2);
    float*  PART_E = (float*)alloc((size_t)B_TOT * NBLK * 128 * 2 * 4);
    float*  PART_P = (float*)alloc((size_t)B_TOT * NBLK * 128 * 2 * 4);
    float*  STATSE = (float*)alloc((size_t)B_TOT * 128 * 2 * 4);
    float*  STATSP = (float*)alloc((size_t)B_TOT * 128 * 2 * 4);
    half_t* WAR    = (half_t*)alloc((size_t)WARENA_N * 2);

    if ((size_t)(wp - (char*)d_ws) > ws_size) {
        fprintf(stderr, "kernel_launch: ws too small (%zu < %zu)\n",
                ws_size, (size_t)(wp - (char*)d_ws));
        return;
    }

    dim3 blk256(256), blk512(512);
    dim3 gI(NBLK, B_TOT);
    dim3 gE2(NBLK, 2, B_TOT);
    dim3 gT((E_TOT + 255) / 256, 1, B_TOT);
    dim3 gN8(NBLK, 8, B_TOT);
    dim3 gN4(NBLK, 4, B_TOT);
    int gA2 = (int)((2 * (long)B_TOT * EB * 16 + 255) / 256);

    // 1-2: prep
    wprep_k<<<dim3(320, 10, 1), blk256, 0, stream>>>(WAR,
        w_e1, w_p1, w_e2, w_p2, wat, wbt, wa, wb, wal, wbl, waf, wbf);
    transpose_in_k<<<gT, blk256, 0, stream>>>(fe, FET);

    // 3-5: layer 1 (both branches)
    mesh1_both_k<<<gI, blk512, 0, stream>>>(FET, gemm, WAR, b_e1, b_p1,
        TMP_E, TMP_P, PART_E, PART_P);
    stats2_k<<<512, blk256, 0, stream>>>(PART_E, PART_P, STATSE, STATSP);
    norm_act2_k<<<gA2, blk256, 0, stream>>>(TMP_E, TMP_P, STATSE, STATSP, X1E, X1P);

    // 6-8: layer 2 (R5 schedule) + norm/res
    mesh2_k<<<gE2, blk512, 0, stream>>>(X1E, X1P, gemm, WAR, b_e2, b_p2,
        TMP_E, TMP_P, PART_E, PART_P);
    stats2_k<<<512, blk256, 0, stream>>>(PART_E, PART_P, STATSE, STATSP);
    normres2_k<<<gN8, blk256, 0, stream>>>(TMP_E, TMP_P, X1E, X1P, STATSE, STATSP,
        out, X2E, X2P);

    // 9: x_all
    xall_k<<<gE2, blk256, 0, stream>>>(X2E, X2P, WAR, ba, bb, XALL);

    // 10: decoder heads + gates (fused; xa2/xb2 stay in LDS)
    heads_gates_k<<<gI, blk512, 0, stream>>>(XALL, gemm, WAR,
        bal, bbl, bat, bbt, baf, bbf, TMP_E, TMP_P, PART_E, PART_P);

    // 11-12: gate stats + aggregate
    stats2_k<<<512, blk256, 0, stream>>>(PART_E, PART_P, STATSE, STATSP);
    gate_agg2_k<<<gN4, blk256, 0, stream>>>(TMP_E, TMP_P, STATSE, STATSP,
        X2E, X2P, out);
}

// Round 9
// 309.265 us; speedup vs baseline: 1.2149x; 1.1185x over previous
//
#include <hip/hip_runtime.h>
#include <cstdio>
#include <math.h>

// ---------------------------------------------------------------------------
// MeshEncoderDecoder — round 9: inorm fused into mesh2 gather staging via
// per-channel f16 (scale,shift); norm_act2 + X1 eliminated. xall GEMM fused
// into normres (x2 tile reused from LDS). 11 launches.
// ---------------------------------------------------------------------------

#define E_TOT 50000
#define B_TOT 2
#define TILE_E 64
#define NBLK ((E_TOT + TILE_E - 1) / TILE_E)   // 782
#define TPAD 67                                // Tf row stride (conflict-tamed)

typedef _Float16 half_t;
typedef __attribute__((ext_vector_type(4))) _Float16 h4;
typedef __attribute__((ext_vector_type(8))) _Float16 h8;
typedef __attribute__((ext_vector_type(4))) float f32x4;

__device__ __forceinline__ float sigmoidf_(float x) {
    return 1.0f / (1.0f + __expf(-x));
}
__device__ __forceinline__ h8 habs8(h8 x) {
    union { h8 h; unsigned int u[4]; } v;
    v.h = x;
#pragma unroll
    for (int i = 0; i < 4; ++i) v.u[i] &= 0x7FFF7FFFu;
    return v.h;
}
__device__ __forceinline__ h8 hmax0(h8 x) {
#if defined(__has_builtin) && __has_builtin(__builtin_elementwise_max)
    h8 z = {};
    return __builtin_elementwise_max(x, z);
#else
    h8 r;
#pragma unroll
    for (int j = 0; j < 8; ++j) r[j] = (x[j] > (half_t)0) ? x[j] : (half_t)0;
    return r;
#endif
}

// ---------------------------------------------------------------------------
// weight arena offsets (halves)
// ---------------------------------------------------------------------------
#define OFF_W1E   0          // 128*64 (k = s*8+cc, zero-padded)
#define OFF_W1P   8192       // 128*64
#define OFF_WTE2  16384      // 128*5*128
#define OFF_WTP2  98304      // 128*5*128
#define OFF_WHA   180224     // 128*5*64 (o<64: wal in s0; o>=64: wat)
#define OFF_WHB   221184     // 128*5*64
#define OFF_WTA   262144     // 32*128
#define OFF_WTB   266240     // 32*128
#define OFF_WTAF  270336     // 128*128
#define OFF_WTBF  286720     // 128*128
#define WARENA_N  303104

__global__ __launch_bounds__(256)
void wprep_k(half_t* __restrict__ wa_,
             const float* __restrict__ w_e1, const float* __restrict__ w_p1,
             const float* __restrict__ w_e2, const float* __restrict__ w_p2,
             const float* __restrict__ wat,  const float* __restrict__ wbt,
             const float* __restrict__ wa,   const float* __restrict__ wb,
             const float* __restrict__ wal,  const float* __restrict__ wbl,
             const float* __restrict__ waf,  const float* __restrict__ wbf)
{
    int idx = blockIdx.x * 256 + threadIdx.x;
    switch (blockIdx.y) {
    case 0: if (idx < 8192) { int o = idx >> 6, k = idx & 63, s = k >> 3, cc = k & 7;
            float v = (s < 5 && cc < 5) ? w_e1[o * 25 + cc * 5 + s] : 0.f;
            wa_[OFF_W1E + idx] = (half_t)v; } break;
    case 1: if (idx < 8192) { int o = idx >> 6, k = idx & 63, s = k >> 3, cc = k & 7;
            float v = (s < 5 && cc >= 5) ? w_p1[o * 15 + (cc - 5) * 5 + s] : 0.f;
            wa_[OFF_W1P + idx] = (half_t)v; } break;
    case 2: if (idx < 81920) { int o = idx / 640, r = idx % 640, s = r >> 7, c = r & 127;
            wa_[OFF_WTE2 + idx] = (half_t)w_e2[(o * 128 + c) * 5 + s]; } break;
    case 3: if (idx < 81920) { int o = idx / 640, r = idx % 640, s = r >> 7, c = r & 127;
            wa_[OFF_WTP2 + idx] = (half_t)w_p2[(o * 128 + c) * 5 + s]; } break;
    case 4: if (idx < 40960) { int o = idx / 320, r = idx % 320, s = r >> 6, c = r & 63;
            float v = (o < 64) ? (s == 0 ? wal[o * 64 + c] : 0.f)
                               : wat[((o - 64) * 64 + c) * 5 + s];
            wa_[OFF_WHA + idx] = (half_t)v; } break;
    case 5: if (idx < 40960) { int o = idx / 320, r = idx % 320, s = r >> 6, c = r & 63;
            float v = (o < 64) ? (s == 0 ? wbl[o * 64 + c] : 0.f)
                               : wbt[((o - 64) * 64 + c) * 5 + s];
            wa_[OFF_WHB + idx] = (half_t)v; } break;
    case 6: if (idx < 4096)  wa_[OFF_WTA  + idx] = (half_t)wa[idx];  break;
    case 7: if (idx < 4096)  wa_[OFF_WTB  + idx] = (half_t)wb[idx];  break;
    case 8: if (idx < 16384) wa_[OFF_WTAF + idx] = (half_t)waf[idx]; break;
    case 9: if (idx < 16384) wa_[OFF_WTBF + idx] = (half_t)wbf[idx]; break;
    }
}

// ---------------------------------------------------------------------------
// transpose fe (b, 8, E) -> fe_t (b, E, 8) f32
// ---------------------------------------------------------------------------
__global__ __launch_bounds__(256)
void transpose_in_k(const float* __restrict__ fe, float* __restrict__ fet)
{
    int b = blockIdx.z;
    int e = blockIdx.x * 256 + threadIdx.x;
    if (e >= E_TOT) return;
    float v[8];
#pragma unroll
    for (int c = 0; c < 8; ++c)
        v[c] = fe[((long)b * 8 + c) * E_TOT + e];
    float4* dst = (float4*)&fet[((long)b * E_TOT + e) * 8];
    dst[0] = make_float4(v[0], v[1], v[2], v[3]);
    dst[1] = make_float4(v[4], v[5], v[6], v[7]);
}

// ---------------------------------------------------------------------------
// layer-1 both branches: shared G, K=64, 8 waves (0-3 edge, 4-7 point)
// ---------------------------------------------------------------------------
__global__ __launch_bounds__(512)
void mesh1_both_k(const float* __restrict__ fet, const int* __restrict__ gemm,
                  const half_t* __restrict__ war,
                  const float* __restrict__ be1, const float* __restrict__ bp1,
                  half_t* __restrict__ tmpe, half_t* __restrict__ tmpp,
                  float* __restrict__ parte, float* __restrict__ partp)
{
    __shared__ h8 Gl[64 * 8];
    __shared__ int nidx[64][4];

    const int tid  = threadIdx.x;
    const int b    = blockIdx.y;
    const int e0   = blockIdx.x * TILE_E;
    const int lane = tid & 63;
    const int wv   = tid >> 6;
    const int l15  = lane & 15;
    const int kg   = lane >> 4;
    const int br   = wv >> 2;
    const int o0   = (wv & 3) * 32;

    const float* xb = fet + (long)b * E_TOT * 8;

    if (tid < 256) {
        int e = tid >> 2, s = tid & 3;
        int eg = e0 + e;
        nidx[e][s] = (eg < E_TOT) ? gemm[((long)b * E_TOT + eg) * 4 + s] : 0;
    }
    __syncthreads();

    {
        int e = tid >> 3, g = tid & 7;
        int eg = e0 + e;
        int se = (eg < E_TOT) ? eg : 0;
        h8 r;
        if (g == 0) {
            const float* p = xb + (long)se * 8;
            float4 v0 = *(const float4*)p, v1 = *(const float4*)(p + 4);
            r[0] = (half_t)v0.x; r[1] = (half_t)v0.y; r[2] = (half_t)v0.z; r[3] = (half_t)v0.w;
            r[4] = (half_t)v1.x; r[5] = (half_t)v1.y; r[6] = (half_t)v1.z; r[7] = (half_t)v1.w;
        } else if (g <= 4) {
            int ia = (g == 1 || g == 3) ? 0 : 1;
            const float* pa = xb + (long)nidx[e][ia] * 8;
            const float* pb = xb + (long)nidx[e][ia + 2] * 8;
            float4 a0 = *(const float4*)pa, a1 = *(const float4*)(pa + 4);
            float4 b0 = *(const float4*)pb, b1 = *(const float4*)(pb + 4);
            float aa[8] = {a0.x, a0.y, a0.z, a0.w, a1.x, a1.y, a1.z, a1.w};
            float bb[8] = {b0.x, b0.y, b0.z, b0.w, b1.x, b1.y, b1.z, b1.w};
            if (g <= 2) {
#pragma unroll
                for (int j = 0; j < 8; ++j) r[j] = (half_t)(aa[j] + bb[j]);
            } else {
#pragma unroll
                for (int j = 0; j < 8; ++j) r[j] = (half_t)fabsf(aa[j] - bb[j]);
            }
        } else {
#pragma unroll
            for (int j = 0; j < 8; ++j) r[j] = (half_t)0.f;
        }
        Gl[(e * 8 + g) ^ (e & 7)] = r;
    }
    __syncthreads();

    f32x4 acc[4][2];
#pragma unroll
    for (int mt = 0; mt < 4; ++mt)
#pragma unroll
        for (int nt = 0; nt < 2; ++nt)
#pragma unroll
            for (int j = 0; j < 4; ++j) acc[mt][nt][j] = 0.f;

    const half_t* wt = war + (br ? OFF_W1P : OFF_W1E);
#pragma unroll
    for (int ks = 0; ks < 2; ++ks) {
        h8 bw[2];
#pragma unroll
        for (int nt = 0; nt < 2; ++nt)
            bw[nt] = *(const h8*)(wt + (long)(o0 + nt * 16 + l15) * 64 + ks * 32 + kg * 8);
#pragma unroll
        for (int mt = 0; mt < 4; ++mt) {
            int row = mt * 16 + l15;
            h8 a = Gl[row * 8 + ((ks * 4 + kg) ^ (row & 7))];
#pragma unroll
            for (int nt = 0; nt < 2; ++nt)
                acc[mt][nt] = __builtin_amdgcn_mfma_f32_16x16x32_f16(a, bw[nt], acc[mt][nt], 0, 0, 0);
        }
    }

    const float* bias = br ? bp1 : be1;
    half_t* yb = (br ? tmpp : tmpe) + (long)b * E_TOT * 128;
    float* part = br ? partp : parte;
    float bv[2], s1[2], s2[2];
#pragma unroll
    for (int nt = 0; nt < 2; ++nt) {
        bv[nt] = bias[o0 + nt * 16 + l15];
        s1[nt] = 0.f; s2[nt] = 0.f;
    }
#pragma unroll
    for (int mt = 0; mt < 4; ++mt) {
        int ebase = e0 + mt * 16 + (kg << 2);
#pragma unroll
        for (int j = 0; j < 4; ++j) {
            if (ebase + j < E_TOT) {
#pragma unroll
                for (int nt = 0; nt < 2; ++nt) {
                    float v = acc[mt][nt][j] + bv[nt];
                    yb[(long)(ebase + j) * 128 + o0 + nt * 16 + l15] = (half_t)v;
                    s1[nt] += v; s2[nt] += v * v;
                }
            }
        }
    }
#pragma unroll
    for (int nt = 0; nt < 2; ++nt) {
        s1[nt] += __shfl_xor(s1[nt], 16); s1[nt] += __shfl_xor(s1[nt], 32);
        s2[nt] += __shfl_xor(s2[nt], 16); s2[nt] += __shfl_xor(s2[nt], 32);
    }
    if (lane < 16) {
        long pb = ((long)b * NBLK + blockIdx.x) * 128;
#pragma unroll
        for (int nt = 0; nt < 2; ++nt) {
            part[(pb + o0 + nt * 16 + lane) * 2 + 0] = s1[nt];
            part[(pb + o0 + nt * 16 + lane) * 2 + 1] = s2[nt];
        }
    }
}

// ---------------------------------------------------------------------------
// layer-2 mesh conv — R5-best schedule + FUSED input norm: x1 = relu(tmp1*sc+sf)
// applied during gather staging via packed-f16 fma. statsh: [b][2][128] halves
// (scales then shifts). One branch per block, 8 waves, 33 KB LDS.
// ---------------------------------------------------------------------------
__global__ __launch_bounds__(512)
void mesh2_k(const half_t* __restrict__ tmp1e, const half_t* __restrict__ tmp1p,
             const half_t* __restrict__ statshe, const half_t* __restrict__ statshp,
             const int* __restrict__ gemm, const half_t* __restrict__ war,
             const float* __restrict__ be, const float* __restrict__ bp,
             half_t* __restrict__ tmp2e, half_t* __restrict__ tmp2p,
             float* __restrict__ parte, float* __restrict__ partp)
{
    __shared__ h8 GlA[64 * 16];
    __shared__ h8 GlB[64 * 16];
    __shared__ int nidx[64][4];

    const int tid  = threadIdx.x;
    const int br   = blockIdx.y;
    const int b    = blockIdx.z;
    const int e0   = blockIdx.x * TILE_E;
    const int lane = tid & 63;
    const int wv   = tid >> 6;
    const int l15  = lane & 15;
    const int kg   = lane >> 4;
    const int o0   = wv * 16;

    const half_t* xb = (br ? tmp1p : tmp1e) + (long)b * E_TOT * 128;
    const half_t* sh = (br ? statshp : statshe) + (long)b * 256;
    const half_t* wt = war + (br ? OFF_WTP2 : OFF_WTE2);

    // per-thread channel stats (c8 = tid & 15 identical for both slots)
    const int tc0 = tid & 15;
    const h8 sc8 = *(const h8*)(sh + tc0 * 8);
    const h8 sf8 = *(const h8*)(sh + 128 + tc0 * 8);

    if (tid < 256) {
        int e = tid >> 2, s = tid & 3;
        int eg = e0 + e;
        nidx[e][s] = (eg < E_TOT) ? gemm[((long)b * E_TOT + eg) * 4 + s] : 0;
    }

    auto nrm = [&](h8 v) -> h8 { return hmax0(v * sc8 + sf8); };

    auto stage_self = [&](h8* dst) {
#pragma unroll
        for (int t = 0; t < 2; ++t) {
            int q = t * 512 + tid;
            int e = q >> 4, c8 = q & 15;
            int eg = e0 + e;
            int se = (eg < E_TOT) ? eg : 0;
            dst[(e * 16 + c8) ^ (e & 7)] = nrm(*(const h8*)(xb + (long)se * 128 + c8 * 8));
        }
    };
    auto stage_pair = [&](h8* dstS, h8* dstD, int ia, int ib) {
#pragma unroll
        for (int t = 0; t < 2; ++t) {
            int q = t * 512 + tid;
            int e = q >> 4, c8 = q & 15;
            int na = nidx[e][ia], nb = nidx[e][ib];
            h8 a  = nrm(*(const h8*)(xb + (long)na * 128 + c8 * 8));
            h8 bq = nrm(*(const h8*)(xb + (long)nb * 128 + c8 * 8));
            int slot = (e * 16 + c8) ^ (e & 7);
            dstS[slot] = a + bq;
            dstD[slot] = habs8(a - bq);
        }
    };

    f32x4 acc[4];
#pragma unroll
    for (int mt = 0; mt < 4; ++mt)
#pragma unroll
        for (int j = 0; j < 4; ++j) acc[mt][j] = 0.f;

    auto compute_chunk = [&](const h8* buf, int s) {
#pragma unroll
        for (int ks = 0; ks < 4; ++ks) {
            h8 bw = *(const h8*)(wt + ((long)(o0 + l15) * 5 + s) * 128 + ks * 32 + kg * 8);
#pragma unroll
            for (int mt = 0; mt < 4; ++mt) {
                int row = mt * 16 + l15;
                h8 a = buf[row * 16 + ((ks * 4 + kg) ^ (row & 7))];
                acc[mt] = __builtin_amdgcn_mfma_f32_16x16x32_f16(a, bw, acc[mt], 0, 0, 0);
            }
        }
    };

    stage_self(GlA);
    __syncthreads();
    compute_chunk(GlA, 0);
    __syncthreads();
    stage_pair(GlA, GlB, 0, 2);
    __syncthreads();
    compute_chunk(GlA, 1);
    compute_chunk(GlB, 3);
    __syncthreads();
    stage_pair(GlA, GlB, 1, 3);
    __syncthreads();
    compute_chunk(GlA, 2);
    compute_chunk(GlB, 4);

    const float* bias = br ? bp : be;
    half_t* yb = (br ? tmp2p : tmp2e) + (long)b * E_TOT * 128;
    float* part = br ? partp : parte;
    float bv = bias[o0 + l15];
    float s1 = 0.f, s2 = 0.f;
#pragma unroll
    for (int mt = 0; mt < 4; ++mt) {
        int ebase = e0 + mt * 16 + (kg << 2);
#pragma unroll
        for (int j = 0; j < 4; ++j) {
            if (ebase + j < E_TOT) {
                float v = acc[mt][j] + bv;
                yb[(long)(ebase + j) * 128 + o0 + l15] = (half_t)v;
                s1 += v; s2 += v * v;
            }
        }
    }
    s1 += __shfl_xor(s1, 16); s1 += __shfl_xor(s1, 32);
    s2 += __shfl_xor(s2, 16); s2 += __shfl_xor(s2, 32);
    if (lane < 16) {
        long pb = ((long)b * NBLK + blockIdx.x) * 128;
        part[(pb + o0 + lane) * 2 + 0] = s1;
        part[(pb + o0 + lane) * 2 + 1] = s2;
    }
}

// ---------------------------------------------------------------------------
// FUSED normres + xall: x2 = relu(norm2(tmp2) + relu(norm1(tmp1))) computed
// once; written as f32 channel-major out section + f16 edge-major copy; the
// 128->32 xall GEMM runs from the LDS x2 tile. blockIdx.y = branch.
// ---------------------------------------------------------------------------
__global__ __launch_bounds__(512)
void normres_xall_k(const half_t* __restrict__ tmp2e, const half_t* __restrict__ tmp2p,
                    const half_t* __restrict__ tmp1e, const half_t* __restrict__ tmp1p,
                    const half_t* __restrict__ sh1e, const half_t* __restrict__ sh1p,
                    const half_t* __restrict__ sh2e, const half_t* __restrict__ sh2p,
                    const half_t* __restrict__ war,
                    const float* __restrict__ ba, const float* __restrict__ bb,
                    float* __restrict__ outb,
                    half_t* __restrict__ x2e, half_t* __restrict__ x2p,
                    half_t* __restrict__ xall)
{
    __shared__ float Tf[128 * TPAD];   // ~34.3 KB
    __shared__ h8 X2t[1024];           // 16 KB

    const int tid  = threadIdx.x;
    const int br   = blockIdx.y;
    const int b    = blockIdx.z;
    const int e0   = blockIdx.x * TILE_E;
    const int lane = tid & 63;
    const int wv   = tid >> 6;
    const int l15  = lane & 15;
    const int kg   = lane >> 4;

    const half_t* t2 = (br ? tmp2p : tmp2e) + (long)b * E_TOT * 128;
    const half_t* t1 = (br ? tmp1p : tmp1e) + (long)b * E_TOT * 128;
    const half_t* s1p = (br ? sh1p : sh1e) + (long)b * 256;
    const half_t* s2p = (br ? sh2p : sh2e) + (long)b * 256;
    half_t* x2g = (br ? x2p : x2e) + (long)b * E_TOT * 128;

    const int tc0 = tid & 15;
    const h8 sc1 = *(const h8*)(s1p + tc0 * 8);
    const h8 sf1 = *(const h8*)(s1p + 128 + tc0 * 8);
    const h8 sc2 = *(const h8*)(s2p + tc0 * 8);
    const h8 sf2 = *(const h8*)(s2p + 128 + tc0 * 8);

#pragma unroll
    for (int t = 0; t < 2; ++t) {
        int q = t * 512 + tid;
        int e = q >> 4;
        int eg = e0 + e;
        int se = (eg < E_TOT) ? eg : (E_TOT - 1);
        h8 v2 = *(const h8*)(t2 + (long)se * 128 + tc0 * 8);
        h8 v1 = *(const h8*)(t1 + (long)se * 128 + tc0 * 8);
        h8 x1 = hmax0(v1 * sc1 + sf1);
        h8 x2 = hmax0(v2 * sc2 + sf2 + x1);
        X2t[(e * 16 + tc0) ^ (e & 7)] = x2;
        if (eg < E_TOT) *(h8*)(x2g + (long)eg * 128 + tc0 * 8) = x2;
#pragma unroll
        for (int j = 0; j < 8; ++j)
            Tf[(tc0 * 8 + j) * TPAD + e] = (float)x2[j];
    }
    __syncthreads();

    // ---- out channel-major write (f32)
#pragma unroll
    for (int i = 0; i < 4; ++i) {
        int task = i * 512 + tid;
        int cl = task >> 4, eq = task & 15;
        int e4 = e0 + eq * 4;
        float4 v = *(const float4*)&Tf[cl * TPAD + eq * 4];
        int cglob = br * 128 + cl;
        long obase = ((long)b * 384 + cglob) * E_TOT + e4;
        if (e4 + 3 < E_TOT) {
            *(float4*)&outb[obase] = v;
        } else {
            const float* vp = &v.x;
            for (int j = 0; j < 4; ++j)
                if (e4 + j < E_TOT) outb[obase + j] = vp[j];
        }
    }

    // ---- xall GEMM from LDS tile: 8 waves = 4 e-quadrants x 2 o-groups(16)
    const int eoff = (wv & 3) * 16;
    const int og   = wv >> 2;
    const half_t* wt = war + (br ? OFF_WTB : OFF_WTA);
    f32x4 acc;
#pragma unroll
    for (int j = 0; j < 4; ++j) acc[j] = 0.f;
#pragma unroll
    for (int ks = 0; ks < 4; ++ks) {
        h8 bw = *(const h8*)(wt + (long)(og * 16 + l15) * 128 + ks * 32 + kg * 8);
        int row = eoff + l15;
        h8 a = X2t[row * 16 + ((ks * 4 + kg) ^ (row & 7))];
        acc = __builtin_amdgcn_mfma_f32_16x16x32_f16(a, bw, acc, 0, 0, 0);
    }
    float bv = (br ? bb : ba)[og * 16 + l15];
    half_t* yall = xall + (long)b * E_TOT * 64;
#pragma unroll
    for (int j = 0; j < 4; ++j) {
        int e = e0 + eoff + (kg << 2) + j;
        if (e < E_TOT)
            yall[(long)e * 64 + br * 32 + og * 16 + l15] = (half_t)(acc[j] + bv);
    }
}

// ---------------------------------------------------------------------------
// FUSED decoder heads + gates (unchanged from R8)
// ---------------------------------------------------------------------------
__global__ __launch_bounds__(512)
void heads_gates_k(const half_t* __restrict__ xall, const int* __restrict__ gemm,
                   const half_t* __restrict__ war,
                   const float* __restrict__ bal, const float* __restrict__ bbl,
                   const float* __restrict__ bat, const float* __restrict__ bbt,
                   const float* __restrict__ baf, const float* __restrict__ bbf,
                   half_t* __restrict__ gA, half_t* __restrict__ gB,
                   float* __restrict__ parte, float* __restrict__ partp)
{
    __shared__ h8 arena[2048];
    __shared__ int nidx[64][4];

    const int tid  = threadIdx.x;
    const int b    = blockIdx.y;
    const int e0   = blockIdx.x * TILE_E;
    const int lane = tid & 63;
    const int wv   = tid >> 6;
    const int hd   = wv >> 2;
    const int o0   = (wv & 3) * 32;
    const int l15  = lane & 15;
    const int kg   = lane >> 4;

    h8* C0 = arena;
    h8* C1 = arena + 512;
    h8* C2 = arena + 1024;

    const half_t* xb = xall + (long)b * E_TOT * 64;

    if (tid < 256) {
        int e = tid >> 2, s = tid & 3;
        int eg = e0 + e;
        nidx[e][s] = (eg < E_TOT) ? gemm[((long)b * E_TOT + eg) * 4 + s] : 0;
    }
    __syncthreads();

    const int te = tid >> 3, tc = tid & 7;
    const int tslot = (te * 8 + tc) ^ (te & 7);

    {
        int eg = e0 + te;
        int se = (eg < E_TOT) ? eg : 0;
        C0[tslot] = *(const h8*)(xb + (long)se * 64 + tc * 8);
    }
    h8 rA, rB;
    {
        rA = *(const h8*)(xb + (long)nidx[te][0] * 64 + tc * 8);
        rB = *(const h8*)(xb + (long)nidx[te][2] * 64 + tc * 8);
    }
    __syncthreads();

    f32x4 acc[4][2];
#pragma unroll
    for (int mt = 0; mt < 4; ++mt)
#pragma unroll
        for (int nt = 0; nt < 2; ++nt)
#pragma unroll
            for (int j = 0; j < 4; ++j) acc[mt][nt][j] = 0.f;

    const half_t* wt = war + (hd ? OFF_WHB : OFF_WHA);
    auto chunk = [&](const h8* buf, int s) {
#pragma unroll
        for (int ks = 0; ks < 2; ++ks) {
            h8 bw0 = *(const h8*)(wt + ((long)(o0 + l15) * 5 + s) * 64 + ks * 32 + kg * 8);
            h8 bw1 = *(const h8*)(wt + ((long)(o0 + 16 + l15) * 5 + s) * 64 + ks * 32 + kg * 8);
#pragma unroll
            for (int mt = 0; mt < 4; ++mt) {
                int row = mt * 16 + l15;
                h8 a = buf[row * 8 + ((ks * 4 + kg) ^ (row & 7))];
                acc[mt][0] = __builtin_amdgcn_mfma_f32_16x16x32_f16(a, bw0, acc[mt][0], 0, 0, 0);
                acc[mt][1] = __builtin_amdgcn_mfma_f32_16x16x32_f16(a, bw1, acc[mt][1], 0, 0, 0);
            }
        }
    };

    chunk(C0, 0);
    __syncthreads();
    {
        C1[tslot] = rA + rB;
        C2[tslot] = habs8(rA - rB);
        rA = *(const h8*)(xb + (long)nidx[te][1] * 64 + tc * 8);
        rB = *(const h8*)(xb + (long)nidx[te][3] * 64 + tc * 8);
    }
    __syncthreads();
    chunk(C1, 1);
    chunk(C2, 3);
    __syncthreads();
    {
        C1[tslot] = rA + rB;
        C2[tslot] = habs8(rA - rB);
    }
    __syncthreads();
    chunk(C1, 2);
    chunk(C2, 4);
    __syncthreads();

    {
        half_t* X = (half_t*)(arena + hd * 1024);
        float bv[2];
#pragma unroll
        for (int nt = 0; nt < 2; ++nt) {
            int o = o0 + nt * 16 + l15;
            bv[nt] = (o < 64) ? (hd ? bbl[o] : bal[o]) : (hd ? bbt[o - 64] : bat[o - 64]);
        }
#pragma unroll
        for (int mt = 0; mt < 4; ++mt) {
#pragma unroll
            for (int j = 0; j < 4; ++j) {
                int e = mt * 16 + (kg << 2) + j;
#pragma unroll
                for (int nt = 0; nt < 2; ++nt) {
                    int c = o0 + nt * 16 + l15;
                    int slot = (e * 16 + (c >> 3)) ^ (e & 7);
                    X[slot * 8 + (c & 7)] = (half_t)(acc[mt][nt][j] + bv[nt]);
                }
            }
        }
    }
    __syncthreads();

    f32x4 g[4][2];
#pragma unroll
    for (int mt = 0; mt < 4; ++mt)
#pragma unroll
        for (int nt = 0; nt < 2; ++nt)
#pragma unroll
            for (int j = 0; j < 4; ++j) g[mt][nt][j] = 0.f;

    const half_t* wtg = war + (hd ? OFF_WTBF : OFF_WTAF);
    const h8* X = arena + hd * 1024;
#pragma unroll
    for (int ks = 0; ks < 4; ++ks) {
        h8 bw0 = *(const h8*)(wtg + (long)(o0 + l15) * 128 + ks * 32 + kg * 8);
        h8 bw1 = *(const h8*)(wtg + (long)(o0 + 16 + l15) * 128 + ks * 32 + kg * 8);
#pragma unroll
        for (int mt = 0; mt < 4; ++mt) {
            int row = mt * 16 + l15;
            h8 a = X[row * 16 + ((ks * 4 + kg) ^ (row & 7))];
            g[mt][0] = __builtin_amdgcn_mfma_f32_16x16x32_f16(a, bw0, g[mt][0], 0, 0, 0);
            g[mt][1] = __builtin_amdgcn_mfma_f32_16x16x32_f16(a, bw1, g[mt][1], 0, 0, 0);
        }
    }

    const float* biasg = hd ? bbf : baf;
    half_t* yb = (hd ? gB : gA) + (long)b * E_TOT * 128;
    float* part = hd ? partp : parte;
    float bg[2] = {biasg[o0 + l15], biasg[o0 + 16 + l15]};
    float s1[2] = {0.f, 0.f}, s2[2] = {0.f, 0.f};
#pragma unroll
    for (int mt = 0; mt < 4; ++mt) {
        int ebase = e0 + mt * 16 + (kg << 2);
#pragma unroll
        for (int j = 0; j < 4; ++j) {
            if (ebase + j < E_TOT) {
#pragma unroll
                for (int nt = 0; nt < 2; ++nt) {
                    float v = g[mt][nt][j] + bg[nt];
                    yb[(long)(ebase + j) * 128 + o0 + nt * 16 + l15] = (half_t)v;
                    s1[nt] += v; s2[nt] += v * v;
                }
            }
        }
    }
#pragma unroll
    for (int nt = 0; nt < 2; ++nt) {
        s1[nt] += __shfl_xor(s1[nt], 16); s1[nt] += __shfl_xor(s1[nt], 32);
        s2[nt] += __shfl_xor(s2[nt], 16); s2[nt] += __shfl_xor(s2[nt], 32);
    }
    if (lane < 16) {
        long pb = ((long)b * NBLK + blockIdx.x) * 128;
#pragma unroll
        for (int nt = 0; nt < 2; ++nt) {
            part[(pb + o0 + nt * 16 + lane) * 2 + 0] = s1[nt];
            part[(pb + o0 + nt * 16 + lane) * 2 + 1] = s2[nt];
        }
    }
}

// ---------------------------------------------------------------------------
// stats finalize: f32 (mean,rstd) + f16 (scale, shift=-mean*rstd) [b][2][128]
// ---------------------------------------------------------------------------
__global__ __launch_bounds__(256)
void stats2_k(const float* __restrict__ parte, const float* __restrict__ partp,
              float* __restrict__ statse, float* __restrict__ statsp,
              half_t* __restrict__ statshe, half_t* __restrict__ statshp)
{
    int g = blockIdx.x;
    int br = g >> 8, rem = g & 255, b = rem >> 7, o = rem & 127;
    const float* part = br ? partp : parte;
    float* stats = br ? statsp : statse;
    half_t* statsh = br ? statshp : statshe;
    int tid = threadIdx.x;
    float s1 = 0.f, s2 = 0.f;
    for (int k = tid; k < NBLK; k += 256) {
        long base = (((long)b * NBLK + k) * 128 + o) * 2;
        s1 += part[base];
        s2 += part[base + 1];
    }
#pragma unroll
    for (int d = 1; d < 64; d <<= 1) {
        s1 += __shfl_xor(s1, d);
        s2 += __shfl_xor(s2, d);
    }
    __shared__ float r1[4], r2[4];
    int wv = tid >> 6;
    if ((tid & 63) == 0) { r1[wv] = s1; r2[wv] = s2; }
    __syncthreads();
    if (tid == 0) {
        s1 = r1[0] + r1[1] + r1[2] + r1[3];
        s2 = r2[0] + r2[1] + r2[2] + r2[3];
        float mean = s1 / (float)E_TOT;
        float var  = s2 / (float)E_TOT - mean * mean;
        var = fmaxf(var, 0.f);
        float rstd = rsqrtf(var + 1e-5f);
        stats[(b * 128 + o) * 2 + 0] = mean;
        stats[(b * 128 + o) * 2 + 1] = rstd;
        statsh[b * 256 + o]       = (half_t)rstd;
        statsh[b * 256 + 128 + o] = (half_t)(-mean * rstd);
    }
}

// ---------------------------------------------------------------------------
// fused gates-norm + softmax2 + aggregate (unchanged)
// ---------------------------------------------------------------------------
__global__ __launch_bounds__(256)
void gate_agg2_k(const half_t* __restrict__ tA, const half_t* __restrict__ tB,
                 const float* __restrict__ statsA, const float* __restrict__ statsB,
                 const half_t* __restrict__ x2e, const half_t* __restrict__ x2p,
                 float* __restrict__ outb)
{
    __shared__ float T[32 * 68];
    int b = blockIdx.z, cg = blockIdx.y;
    int e0 = blockIdx.x * 64;
    int tid = threadIdx.x;
#pragma unroll
    for (int i = 0; i < 2; ++i) {
        int q = tid + i * 256;
        int e = q >> 3, cq = q & 7;
        int eg = e0 + e;
        int se = (eg < E_TOT) ? eg : (E_TOT - 1);
        int c = cg * 32 + cq * 4;
        long base = ((long)b * E_TOT + se) * 128 + c;
        h4 a4 = *(const h4*)&tA[base];
        h4 b4 = *(const h4*)&tB[base];
        h4 xe4 = *(const h4*)&x2e[base];
        h4 xp4 = *(const h4*)&x2p[base];
#pragma unroll
        for (int j = 0; j < 4; ++j) {
            float2 sa = *(const float2*)&statsA[(b * 128 + c + j) * 2];
            float2 sb = *(const float2*)&statsB[(b * 128 + c + j) * 2];
            float na = sigmoidf_(((float)a4[j] - sa.x) * sa.y);
            float nb = sigmoidf_(((float)b4[j] - sb.x) * sb.y);
            float s = sigmoidf_(na - nb);
            T[(cq * 4 + j) * 68 + e] = (float)xe4[j] * s + (float)xp4[j] * (1.f - s);
        }
    }
    __syncthreads();
#pragma unroll
    for (int i = 0; i < 2; ++i) {
        int q = tid + i * 256;
        int cl = q >> 4, eq = q & 15;
        int e4 = e0 + eq * 4;
        int cglob = cg * 32 + cl;
        float4 v = *(const float4*)&T[cl * 68 + eq * 4];
        long ab = ((long)b * 384 + 256 + cglob) * E_TOT + e4;
        if (e4 + 3 < E_TOT) {
            *(float4*)&outb[ab] = v;
        } else {
            const float* vp = &v.x;
            for (int j = 0; j < 4; ++j)
                if (e4 + j < E_TOT) outb[ab + j] = vp[j];
        }
    }
}

// ---------------------------------------------------------------------------
extern "C" void kernel_launch(void* const* d_in, const int* in_sizes, int n_in,
                              void* d_out, int out_size, void* d_ws, size_t ws_size,
                              hipStream_t stream)
{
    const float* fe   = (const float*)d_in[0];
    const int*   gemm = (const int*)  d_in[1];
    const float* w_e1 = (const float*)d_in[2];  const float* b_e1 = (const float*)d_in[3];
    const float* w_p1 = (const float*)d_in[4];  const float* b_p1 = (const float*)d_in[5];
    const float* w_e2 = (const float*)d_in[6];  const float* b_e2 = (const float*)d_in[7];
    const float* w_p2 = (const float*)d_in[8];  const float* b_p2 = (const float*)d_in[9];
    const float* wa   = (const float*)d_in[10]; const float* ba   = (const float*)d_in[11];
    const float* wb   = (const float*)d_in[12]; const float* bb   = (const float*)d_in[13];
    const float* wal  = (const float*)d_in[14]; const float* bal  = (const float*)d_in[15];
    const float* wbl  = (const float*)d_in[16]; const float* bbl  = (const float*)d_in[17];
    const float* wat  = (const float*)d_in[18]; const float* bat  = (const float*)d_in[19];
    const float* wbt  = (const float*)d_in[20]; const float* bbt  = (const float*)d_in[21];
    const float* waf  = (const float*)d_in[22]; const float* baf  = (const float*)d_in[23];
    const float* wbf  = (const float*)d_in[24]; const float* bbf  = (const float*)d_in[25];
    float* out = (float*)d_out;

    const long EB = (long)E_TOT;

    char* wp = (char*)d_ws;
    auto alloc = [&](size_t bytes) -> void* {
        void* r = (void*)wp;
        wp += (bytes + 255) & ~(size_t)255;
        return r;
    };
    float*  FET    = (float*)alloc((size_t)B_TOT * EB * 8 * 4);
    half_t* TMP1_E = (half_t*)alloc((size_t)B_TOT * EB * 128 * 2);   // mesh1 out; later gates
    half_t* TMP1_P = (half_t*)alloc((size_t)B_TOT * EB * 128 * 2);
    half_t* TMP2_E = (half_t*)alloc((size_t)B_TOT * EB * 128 * 2);   // mesh2 out
    half_t* TMP2_P = (half_t*)alloc((size_t)B_TOT * EB * 128 * 2);
    half_t* X2E    = (half_t*)alloc((size_t)B_TOT * EB * 128 * 2);
    half_t* X2P    = (half_t*)alloc((size_t)B_TOT * EB * 128 * 2);
    half_t* XALL   = (half_t*)alloc((size_t)B_TOT * EB * 64 * 2);
    float*  PART_E = (float*)alloc((size_t)B_TOT * NBLK * 128 * 2 * 4);
    float*  PART_P = (float*)alloc((size_t)B_TOT * NBLK * 128 * 2 * 4);
    float*  STATSE = (float*)alloc((size_t)B_TOT * 128 * 2 * 4);
    float*  STATSP = (float*)alloc((size_t)B_TOT * 128 * 2 * 4);
    half_t* SH1E   = (half_t*)alloc((size_t)B_TOT * 256 * 2);
    half_t* SH1P   = (half_t*)alloc((size_t)B_TOT * 256 * 2);
    half_t* SH2E   = (half_t*)alloc((size_t)B_TOT * 256 * 2);
    half_t* SH2P   = (half_t*)alloc((size_t)B_TOT * 256 * 2);
    half_t* WAR    = (half_t*)alloc((size_t)WARENA_N * 2);

    if ((size_t)(wp - (char*)d_ws) > ws_size) {
        fprintf(stderr, "kernel_launch: ws too small (%zu < %zu)\n",
                ws_size, (size_t)(wp - (char*)d_ws));
        return;
    }

    dim3 blk256(256), blk512(512);
    dim3 gI(NBLK, B_TOT);
    dim3 gE2(NBLK, 2, B_TOT);
    dim3 gT((E_TOT + 255) / 256, 1, B_TOT);
    dim3 gN4(NBLK, 4, B_TOT);

    // 1-2: prep
    wprep_k<<<dim3(320, 10, 1), blk256, 0, stream>>>(WAR,
        w_e1, w_p1, w_e2, w_p2, wat, wbt, wa, wb, wal, wbl, waf, wbf);
    transpose_in_k<<<gT, blk256, 0, stream>>>(fe, FET);

    // 3-4: layer 1 (both branches) + stats
    mesh1_both_k<<<gI, blk512, 0, stream>>>(FET, gemm, WAR, b_e1, b_p1,
        TMP1_E, TMP1_P, PART_E, PART_P);
    stats2_k<<<512, blk256, 0, stream>>>(PART_E, PART_P, STATSE, STATSP, SH1E, SH1P);

    // 5-6: layer 2 (fused input-norm) + stats
    mesh2_k<<<gE2, blk512, 0, stream>>>(TMP1_E, TMP1_P, SH1E, SH1P, gemm, WAR,
        b_e2, b_p2, TMP2_E, TMP2_P, PART_E, PART_P);
    stats2_k<<<512, blk256, 0, stream>>>(PART_E, PART_P, STATSE, STATSP, SH2E, SH2P);

    // 7: normres + xall (x2 -> out sections, f16 copies, XALL)
    normres_xall_k<<<gE2, blk512, 0, stream>>>(TMP2_E, TMP2_P, TMP1_E, TMP1_P,
        SH1E, SH1P, SH2E, SH2P, WAR, ba, bb, out, X2E, X2P, XALL);

    // 8-9: decoder heads + gates (fused) + gate stats
    heads_gates_k<<<gI, blk512, 0, stream>>>(XALL, gemm, WAR,
        bal, bbl, bat, bbt, baf, bbf, TMP1_E, TMP1_P, PART_E, PART_P);
    stats2_k<<<512, blk256, 0, stream>>>(PART_E, PART_P, STATSE, STATSP, SH1E, SH1P);

    // 10: aggregate
    gate_agg2_k<<<gN4, blk256, 0, stream>>>(TMP1_E, TMP1_P, STATSE, STATSP,
        X2E, X2P, out);
}